// Round 4
// baseline (1717.139 us; speedup 1.0000x reference)
//
#include <hip/hip_runtime.h>

#define N_NODE 200000
#define EMB 64
#define N_EDGES 2000000
#define NROWS_TOTAL (2 * N_NODE)        // both graphs' rows concatenated
#define TOT_E (2 * N_EDGES)
#define BSHIFT 8
#define BROWS 256                        // rows per bucket
#define NBUCK ((NROWS_TOTAL + BROWS - 1) / BROWS)   // 1563

struct Edge { int g; int c; float v; }; // 12B

// out = emb * sigmoid(emb @ W + b), written to two destinations (acc init + u_cur)
__global__ void gate_kernel(const float* __restrict__ emb,
                            const float* __restrict__ W,
                            const float* __restrict__ b,
                            float* __restrict__ out1,
                            float* __restrict__ out2, int n) {
    __shared__ float Wl[64 * 64];
    __shared__ float rowbuf[4][64];
    int t = threadIdx.x;
    for (int k = t; k < 4096; k += 256) Wl[k] = W[k];
    int nl = t >> 6, j = t & 63;
    int i = blockIdx.x * 4 + nl;
    if (i < n) rowbuf[nl][j] = emb[(size_t)i * 64 + j];
    __syncthreads();
    if (i >= n) return;
    float s = b[j];
#pragma unroll
    for (int k = 0; k < 64; ++k) s += rowbuf[nl][k] * Wl[k * 64 + j];
    float g = 1.0f / (1.0f + __expf(-s));
    float val = rowbuf[nl][j] * g;
    out1[(size_t)i * 64 + j] = val;
    out2[(size_t)i * 64 + j] = val;
}

// K1: LDS-aggregated bucket histogram over both graphs
__global__ void bhist_kernel(const int* __restrict__ item_rows,
                             const int* __restrict__ user_rows,
                             int* __restrict__ bcnt) {
    __shared__ int h[NBUCK];
    for (int k = threadIdx.x; k < NBUCK; k += 256) h[k] = 0;
    __syncthreads();
    int stride = gridDim.x * 256;
    for (int i = blockIdx.x * 256 + threadIdx.x; i < TOT_E; i += stride) {
        int g = (i < N_EDGES) ? item_rows[i] : (N_NODE + user_rows[i - N_EDGES]);
        atomicAdd(&h[g >> BSHIFT], 1);
    }
    __syncthreads();
    for (int k = threadIdx.x; k < NBUCK; k += 256) {
        int v = h[k];
        if (v) atomicAdd(&bcnt[k], v);
    }
}

// K2: single-block scan of NBUCK bucket counts -> bbase (exclusive) + cursors
__global__ void bscan_kernel(const int* __restrict__ bcnt, int* __restrict__ bbase,
                             int* __restrict__ bcur, int* __restrict__ row_ptr) {
    __shared__ int sh[1024];
    int t = threadIdx.x;        // 1024 threads, 2 elements each
    int i0 = t * 2;
    int c0 = (i0 < NBUCK) ? bcnt[i0] : 0;
    int c1 = (i0 + 1 < NBUCK) ? bcnt[i0 + 1] : 0;
    int s = c0 + c1;
    sh[t] = s;
    __syncthreads();
    for (int off = 1; off < 1024; off <<= 1) {
        int u = (t >= off) ? sh[t - off] : 0;
        __syncthreads();
        sh[t] += u;
        __syncthreads();
    }
    int excl = sh[t] - s;
    if (i0 < NBUCK) { bbase[i0] = excl; bcur[i0] = excl; }
    if (i0 + 1 < NBUCK) { bbase[i0 + 1] = excl + c0; bcur[i0 + 1] = excl + c0; }
    if (t == 0) { bbase[NBUCK] = TOT_E; row_ptr[NROWS_TOTAL] = TOT_E; }
}

// K3: append edges into bucket staging regions (dense per-bucket writes)
__global__ void append_kernel(const int* __restrict__ item_rows, const int* __restrict__ item_cols,
                              const float* __restrict__ item_vals,
                              const int* __restrict__ user_rows, const int* __restrict__ user_cols,
                              const float* __restrict__ user_vals,
                              int* __restrict__ bcur, Edge* __restrict__ stage) {
    int i = blockIdx.x * 256 + threadIdx.x;
    if (i >= TOT_E) return;
    int g, c; float v;
    if (i < N_EDGES) { g = item_rows[i]; c = item_cols[i]; v = item_vals[i]; }
    else { int j = i - N_EDGES; g = N_NODE + user_rows[j]; c = user_cols[j]; v = user_vals[j]; }
    int pos = atomicAdd(&bcur[g >> BSHIFT], 1);
    Edge e; e.g = g; e.c = c; e.v = v;
    stage[pos] = e;
}

// K4: per-bucket finalize: LDS row-hist + scan -> row_ptr, scatter (col,val) into CSR
__global__ void finalize_kernel(const Edge* __restrict__ stage, const int* __restrict__ bbase,
                                int* __restrict__ row_ptr, int2* __restrict__ ecv) {
    __shared__ int hist[BROWS];
    __shared__ int cur[BROWS];
    __shared__ int wsum[4];
    int b = blockIdx.x;
    int t = threadIdx.x;        // 256 threads == BROWS
    int base = bbase[b], end = bbase[b + 1];
    hist[t] = 0;
    __syncthreads();
    for (int k = base + t; k < end; k += 256)
        atomicAdd(&hist[stage[k].g & (BROWS - 1)], 1);
    __syncthreads();
    int c = hist[t];
    int lane = t & 63, w = t >> 6;
    int incl = c;
#pragma unroll
    for (int off = 1; off < 64; off <<= 1) {
        int u = __shfl_up(incl, off);
        if (lane >= off) incl += u;
    }
    if (lane == 63) wsum[w] = incl;
    __syncthreads();
    int woff = 0;
    for (int k = 0; k < w; ++k) woff += wsum[k];
    int excl = woff + incl - c;
    int g = (b << BSHIFT) + t;
    int start = base + excl;
    if (g < NROWS_TOTAL) row_ptr[g] = start;
    cur[t] = start;
    __syncthreads();
    for (int k = base + t; k < end; k += 256) {
        Edge e = stage[k];
        int pos = atomicAdd(&cur[e.g & (BROWS - 1)], 1);
        ecv[pos] = make_int2(e.c, __float_as_int(e.v));
    }
}

// one wave per row; per-lane edge staging + shfl broadcast + unroll-8 gathers
template <bool WRITE_Y>
__global__ void spmm_norm_acc(const int* __restrict__ row_ptr, const int2* __restrict__ ecv,
                              const float* __restrict__ x,
                              float* __restrict__ y, float* __restrict__ acc, int n) {
    int t = threadIdx.x;
    int lane = t & 63;
    int i = blockIdx.x * 4 + (t >> 6);
    if (i >= n) return;
    int s = row_ptr[i], e = row_ptr[i + 1];
    float a = 0.0f;
    for (int base = s; base < e; base += 64) {
        int idx = base + lane;
        int cl = 0; float vl = 0.0f;
        if (idx < e) { int2 p = ecv[idx]; cl = p.x; vl = __int_as_float(p.y); }
        int cnt = min(64, e - base);
        int cnt8 = (cnt + 7) & ~7;
        for (int k = 0; k < cnt8; k += 8) {
#pragma unroll
            for (int u = 0; u < 8; ++u) {
                int c = __shfl(cl, k + u);
                float v = __shfl(vl, k + u);
                a += v * x[(size_t)c * 64 + lane];   // padding lanes: v=0, c=0 (safe, hot)
            }
        }
    }
    if (WRITE_Y) y[(size_t)i * 64 + lane] = a;
    float sq = a * a;
#pragma unroll
    for (int off = 32; off; off >>= 1) sq += __shfl_xor(sq, off);
    float norm = sqrtf(sq);
    acc[(size_t)i * 64 + lane] += a / fmaxf(norm, 1e-12f);
}

// channel-3 last layer fused with channel attention + mix (no y/acc3 writes)
__global__ void spmm_norm_mix(const int* __restrict__ row_ptr, const int2* __restrict__ ecv,
                              const float* __restrict__ x, const float* __restrict__ acc3,
                              float* __restrict__ mixed, const float* __restrict__ vvec,
                              float* __restrict__ score, int n) {
    int t = threadIdx.x;
    int lane = t & 63;
    int i = blockIdx.x * 4 + (t >> 6);
    if (i >= n) return;
    int s = row_ptr[i], e = row_ptr[i + 1];
    float a = 0.0f;
    for (int base = s; base < e; base += 64) {
        int idx = base + lane;
        int cl = 0; float vl = 0.0f;
        if (idx < e) { int2 p = ecv[idx]; cl = p.x; vl = __int_as_float(p.y); }
        int cnt = min(64, e - base);
        int cnt8 = (cnt + 7) & ~7;
        for (int k = 0; k < cnt8; k += 8) {
#pragma unroll
            for (int u = 0; u < 8; ++u) {
                int c = __shfl(cl, k + u);
                float v = __shfl(vl, k + u);
                a += v * x[(size_t)c * 64 + lane];
            }
        }
    }
    float sq = a * a;
#pragma unroll
    for (int off = 32; off; off >>= 1) sq += __shfl_xor(sq, off);
    float norm = sqrtf(sq);
    float a3 = acc3[(size_t)i * 64 + lane] + a / fmaxf(norm, 1e-12f);
    float a2 = mixed[(size_t)i * 64 + lane];
    float vv = vvec[lane];
    float w2 = a2 * vv, w3 = a3 * vv;
#pragma unroll
    for (int off = 32; off; off >>= 1) {
        w2 += __shfl_xor(w2, off);
        w3 += __shfl_xor(w3, off);
    }
    float m = fmaxf(w2, w3);
    float x2 = __expf(w2 - m), x3 = __expf(w3 - m);
    float inv = 1.0f / (x2 + x3);
    float s2 = x2 * inv, s3 = x3 * inv;
    mixed[(size_t)i * 64 + lane] = s2 * a2 + s3 * a3;
    if (lane == 0) { score[(size_t)i * 2] = s2; score[(size_t)i * 2 + 1] = s3; }
}

// v[k] = sum_j att_m[k][j] * att[j]
__global__ void vvec_kernel(const float* __restrict__ att_m, const float* __restrict__ att,
                            float* __restrict__ v) {
    int k = threadIdx.x;
    float s = 0.0f;
    for (int j = 0; j < 64; ++j) s += att_m[k * 64 + j] * att[j];
    v[k] = s;
}

extern "C" void kernel_launch(void* const* d_in, const int* in_sizes, int n_in,
                              void* d_out, int out_size, void* d_ws, size_t ws_size,
                              hipStream_t stream) {
    const float* user_emb = (const float*)d_in[0];
    const float* W0 = (const float*)d_in[1];
    const float* b0 = (const float*)d_in[2];
    const float* W1 = (const float*)d_in[3];
    const float* b1 = (const float*)d_in[4];
    const float* att = (const float*)d_in[5];
    const float* att_m = (const float*)d_in[6];
    const int* item_rows = (const int*)d_in[7];
    const int* item_cols = (const int*)d_in[8];
    const float* item_vals = (const float*)d_in[9];
    const int* user_rows = (const int*)d_in[10];
    const int* user_cols = (const int*)d_in[11];
    const float* user_vals = (const float*)d_in[12];

    float* out = (float*)d_out;
    float* mixed = out;                          // N*64, doubles as acc2
    float* score = out + (size_t)N_NODE * 64;

    char* w = (char*)d_ws;
    float* acc3 = (float*)w;   w += (size_t)N_NODE * 64 * 4;
    float* u_cur = (float*)w;  w += (size_t)N_NODE * 64 * 4;
    float* u_nxt = (float*)w;  w += (size_t)N_NODE * 64 * 4;   // overlaid by stage during build
    int* row_ptr = (int*)w;    w += ((size_t)NROWS_TOTAL + 2) * 4;
    int2* ecv = (int2*)w;      w += (size_t)TOT_E * 8;
    float* vvec = (float*)w;   w += 256;
    int* bcnt = (int*)w;       w += (NBUCK + 2) * 4;
    int* bbase = (int*)w;      w += (NBUCK + 2) * 4;
    int* bcur = (int*)w;       w += (NBUCK + 2) * 4;
    Edge* stage = (Edge*)u_nxt;                 // 48MB <= 51.2MB, dead before propagate

    const int NB4 = (N_NODE + 3) / 4;
    const int EB2 = (TOT_E + 255) / 256;
    const int* rp_item = row_ptr;
    const int* rp_user = row_ptr + N_NODE;

    // bucketed CSR build for both graphs
    hipMemsetAsync(bcnt, 0, (size_t)NBUCK * 4, stream);
    bhist_kernel<<<1024, 256, 0, stream>>>(item_rows, user_rows, bcnt);
    bscan_kernel<<<1, 1024, 0, stream>>>(bcnt, bbase, bcur, row_ptr);
    append_kernel<<<EB2, 256, 0, stream>>>(item_rows, item_cols, item_vals,
                                           user_rows, user_cols, user_vals, bcur, stage);
    finalize_kernel<<<NBUCK, 256, 0, stream>>>(stage, bbase, row_ptr, ecv);
    vvec_kernel<<<1, 64, 0, stream>>>(att_m, att, vvec);

    // channel 2: item graph, acc lives in d_out (mixed region)
    gate_kernel<<<NB4, 256, 0, stream>>>(user_emb, W0, b0, mixed, u_cur, N_NODE);
    spmm_norm_acc<true><<<NB4, 256, 0, stream>>>(rp_item, ecv, u_cur, u_nxt, mixed, N_NODE);
    spmm_norm_acc<true><<<NB4, 256, 0, stream>>>(rp_item, ecv, u_nxt, u_cur, mixed, N_NODE);
    spmm_norm_acc<false><<<NB4, 256, 0, stream>>>(rp_item, ecv, u_cur, nullptr, mixed, N_NODE);

    // channel 3: user graph
    gate_kernel<<<NB4, 256, 0, stream>>>(user_emb, W1, b1, acc3, u_cur, N_NODE);
    spmm_norm_acc<true><<<NB4, 256, 0, stream>>>(rp_user, ecv, u_cur, u_nxt, acc3, N_NODE);
    spmm_norm_acc<true><<<NB4, 256, 0, stream>>>(rp_user, ecv, u_nxt, u_cur, acc3, N_NODE);
    spmm_norm_mix<<<NB4, 256, 0, stream>>>(rp_user, ecv, u_cur, acc3, mixed, vvec, score, N_NODE);
}

// Round 5
// 1147.587 us; speedup vs baseline: 1.4963x; 1.4963x over previous
//
#include <hip/hip_runtime.h>

#define N_NODE 200000
#define EMB 64
#define N_EDGES 2000000
#define NROWS_TOTAL (2 * N_NODE)        // both graphs' rows concatenated
#define TOT_E (2 * N_EDGES)
#define SCAN_CHUNK 1024
#define SCAN_BLOCKS ((NROWS_TOTAL + SCAN_CHUNK - 1) / SCAN_CHUNK)   // 391
#define NPART 8
#define PART_ROWS (NROWS_TOTAL / NPART)  // 50000 exactly

// out = emb * sigmoid(emb @ W + b), written to two destinations (acc init + u_cur)
__global__ void gate_kernel(const float* __restrict__ emb,
                            const float* __restrict__ W,
                            const float* __restrict__ b,
                            float* __restrict__ out1,
                            float* __restrict__ out2, int n) {
    __shared__ float Wl[64 * 64];
    __shared__ float rowbuf[4][64];
    int t = threadIdx.x;
    for (int k = t; k < 4096; k += 256) Wl[k] = W[k];
    int nl = t >> 6, j = t & 63;
    int i = blockIdx.x * 4 + nl;
    if (i < n) rowbuf[nl][j] = emb[(size_t)i * 64 + j];
    __syncthreads();
    if (i >= n) return;
    float s = b[j];
#pragma unroll
    for (int k = 0; k < 64; ++k) s += rowbuf[nl][k] * Wl[k * 64 + j];
    float g = 1.0f / (1.0f + __expf(-s));
    float val = rowbuf[nl][j] * g;
    out1[(size_t)i * 64 + j] = val;
    out2[(size_t)i * 64 + j] = val;
}

// histogram both graphs into one counter array: item -> cnt[r], user -> cnt[N+r]
__global__ void hist2_kernel(const int* __restrict__ item_rows,
                             const int* __restrict__ user_rows,
                             int* __restrict__ cnt) {
    int i = blockIdx.x * blockDim.x + threadIdx.x;
    if (i < N_EDGES) atomicAdd(&cnt[__builtin_nontemporal_load(&item_rows[i])], 1);
    else if (i < TOT_E) atomicAdd(&cnt[N_NODE + __builtin_nontemporal_load(&user_rows[i - N_EDGES])], 1);
}

// ---- device-wide exclusive scan of cnt[0..NROWS_TOTAL) -> row_ptr & fill ----
__global__ void scan1_kernel(const int* __restrict__ cnt, int* __restrict__ bsum, int n) {
    int t = threadIdx.x;
    int base = blockIdx.x * SCAN_CHUNK + t * 4;
    int s = 0;
#pragma unroll
    for (int k = 0; k < 4; ++k) {
        int i = base + k;
        if (i < n) s += cnt[i];
    }
#pragma unroll
    for (int off = 32; off; off >>= 1) s += __shfl_xor(s, off);
    __shared__ int ws[4];
    int lane = t & 63, w = t >> 6;
    if (lane == 0) ws[w] = s;
    __syncthreads();
    if (t == 0) bsum[blockIdx.x] = ws[0] + ws[1] + ws[2] + ws[3];
}

__global__ void scan2_kernel(const int* __restrict__ bsum, int* __restrict__ boff) {
    __shared__ int sh[512];
    int t = threadIdx.x;   // 512 threads
    int v = (t < SCAN_BLOCKS) ? bsum[t] : 0;
    sh[t] = v;
    __syncthreads();
    for (int off = 1; off < 512; off <<= 1) {
        int u = (t >= off) ? sh[t - off] : 0;
        __syncthreads();
        sh[t] += u;
        __syncthreads();
    }
    if (t < SCAN_BLOCKS) boff[t] = sh[t] - v;   // exclusive
}

__global__ void scan3_kernel(const int* __restrict__ cnt, const int* __restrict__ boff,
                             int* __restrict__ row_ptr, int* __restrict__ fill, int n) {
    int t = threadIdx.x;
    int lane = t & 63, w = t >> 6;
    int base = blockIdx.x * SCAN_CHUNK + t * 4;
    int c[4];
#pragma unroll
    for (int k = 0; k < 4; ++k) {
        int i = base + k;
        c[k] = (i < n) ? cnt[i] : 0;
    }
    int e1 = c[0], e2 = c[0] + c[1], e3 = c[0] + c[1] + c[2];
    int tsum = e3 + c[3];
    int incl = tsum;
#pragma unroll
    for (int off = 1; off < 64; off <<= 1) {
        int u = __shfl_up(incl, off);
        if (lane >= off) incl += u;
    }
    int excl = incl - tsum;
    __shared__ int wsum[4];
    if (lane == 63) wsum[w] = incl;
    __syncthreads();
    int woff = 0;
    for (int k = 0; k < 4; ++k) if (k < w) woff += wsum[k];
    int g = boff[blockIdx.x] + woff + excl;
    int vv[4] = {g, g + e1, g + e2, g + e3};
#pragma unroll
    for (int k = 0; k < 4; ++k) {
        int i = base + k;
        if (i < n) { row_ptr[i] = vv[k]; fill[i] = vv[k]; }
    }
    if (blockIdx.x == 0 && t == 0) row_ptr[n] = TOT_E;
}

// XCD-partitioned scatter: blocks with blockIdx%8==p own row range [p*50000, (p+1)*50000)
// -> each XCD's random writes confined to a ~4MB L2-resident window.
__global__ void scatterP_kernel(const int* __restrict__ item_rows, const int* __restrict__ item_cols,
                                const float* __restrict__ item_vals,
                                const int* __restrict__ user_rows, const int* __restrict__ user_cols,
                                const float* __restrict__ user_vals,
                                int* __restrict__ fill, int2* __restrict__ ecv) {
    int part = blockIdx.x & (NPART - 1);
    int sub = blockIdx.x >> 3;
    int nsub = gridDim.x >> 3;
    int glo = part * PART_ROWS;
    int ghi = glo + PART_ROWS;
    int stride = nsub * 256;
    for (int i = sub * 256 + threadIdx.x; i < TOT_E; i += stride) {
        int g;
        if (i < N_EDGES) g = __builtin_nontemporal_load(&item_rows[i]);
        else g = N_NODE + __builtin_nontemporal_load(&user_rows[i - N_EDGES]);
        if (g < glo || g >= ghi) continue;
        int c; float v;
        if (i < N_EDGES) {
            c = __builtin_nontemporal_load(&item_cols[i]);
            v = __builtin_nontemporal_load(&item_vals[i]);
        } else {
            c = __builtin_nontemporal_load(&user_cols[i - N_EDGES]);
            v = __builtin_nontemporal_load(&user_vals[i - N_EDGES]);
        }
        int pos = atomicAdd(&fill[g], 1);
        ecv[pos] = make_int2(c, __float_as_int(v));
    }
}

// 16 lanes per row, 4 rows per wave, float4 per lane.
template <bool WRITE_Y>
__global__ void spmm_norm_acc(const int* __restrict__ row_ptr, const int2* __restrict__ ecv,
                              const float* __restrict__ x,
                              float* __restrict__ y, float* __restrict__ acc, int n) {
    int t = threadIdx.x;
    int lane = t & 63;
    int sub = lane >> 4;
    int l16 = lane & 15;
    int i = blockIdx.x * 16 + (t >> 6) * 4 + sub;
    if (i >= n) return;
    int s = row_ptr[i], e = row_ptr[i + 1];
    const float4* x4 = (const float4*)x;
    float4 a = make_float4(0.f, 0.f, 0.f, 0.f);
    int gbase = sub * 16;
    for (int base = s; base < e; base += 16) {
        int idx = base + l16;
        int cl = 0; float vl = 0.0f;
        if (idx < e) { int2 p = ecv[idx]; cl = p.x; vl = __int_as_float(p.y); }
        int cnt = min(16, e - base);
        int cnt4 = (cnt + 3) & ~3;
        for (int k = 0; k < cnt4; k += 4) {
#pragma unroll
            for (int u = 0; u < 4; ++u) {
                int c = __shfl(cl, gbase + k + u);
                float v = __shfl(vl, gbase + k + u);
                float4 xv = x4[(size_t)c * 16 + l16];
                a.x += v * xv.x; a.y += v * xv.y; a.z += v * xv.z; a.w += v * xv.w;
            }
        }
    }
    size_t o4 = (size_t)i * 16 + l16;
    if (WRITE_Y) ((float4*)y)[o4] = a;
    float sq = a.x * a.x + a.y * a.y + a.z * a.z + a.w * a.w;
#pragma unroll
    for (int off = 8; off; off >>= 1) sq += __shfl_xor(sq, off);
    float rinv = 1.0f / fmaxf(sqrtf(sq), 1e-12f);
    float4* acc4 = (float4*)acc;
    float4 aa = acc4[o4];
    aa.x += a.x * rinv; aa.y += a.y * rinv; aa.z += a.z * rinv; aa.w += a.w * rinv;
    acc4[o4] = aa;
}

// channel-3 last layer fused with channel attention + mix
__global__ void spmm_norm_mix(const int* __restrict__ row_ptr, const int2* __restrict__ ecv,
                              const float* __restrict__ x, const float* __restrict__ acc3,
                              float* __restrict__ mixed, const float* __restrict__ vvec,
                              float* __restrict__ score, int n) {
    int t = threadIdx.x;
    int lane = t & 63;
    int sub = lane >> 4;
    int l16 = lane & 15;
    int i = blockIdx.x * 16 + (t >> 6) * 4 + sub;
    if (i >= n) return;
    int s = row_ptr[i], e = row_ptr[i + 1];
    const float4* x4 = (const float4*)x;
    float4 a = make_float4(0.f, 0.f, 0.f, 0.f);
    int gbase = sub * 16;
    for (int base = s; base < e; base += 16) {
        int idx = base + l16;
        int cl = 0; float vl = 0.0f;
        if (idx < e) { int2 p = ecv[idx]; cl = p.x; vl = __int_as_float(p.y); }
        int cnt = min(16, e - base);
        int cnt4 = (cnt + 3) & ~3;
        for (int k = 0; k < cnt4; k += 4) {
#pragma unroll
            for (int u = 0; u < 4; ++u) {
                int c = __shfl(cl, gbase + k + u);
                float v = __shfl(vl, gbase + k + u);
                float4 xv = x4[(size_t)c * 16 + l16];
                a.x += v * xv.x; a.y += v * xv.y; a.z += v * xv.z; a.w += v * xv.w;
            }
        }
    }
    float sq = a.x * a.x + a.y * a.y + a.z * a.z + a.w * a.w;
#pragma unroll
    for (int off = 8; off; off >>= 1) sq += __shfl_xor(sq, off);
    float rinv = 1.0f / fmaxf(sqrtf(sq), 1e-12f);
    size_t o4 = (size_t)i * 16 + l16;
    float4 a3 = ((const float4*)acc3)[o4];
    a3.x += a.x * rinv; a3.y += a.y * rinv; a3.z += a.z * rinv; a3.w += a.w * rinv;
    float4 a2 = ((float4*)mixed)[o4];
    float4 vv = ((const float4*)vvec)[l16];
    float w2 = a2.x * vv.x + a2.y * vv.y + a2.z * vv.z + a2.w * vv.w;
    float w3 = a3.x * vv.x + a3.y * vv.y + a3.z * vv.z + a3.w * vv.w;
#pragma unroll
    for (int off = 8; off; off >>= 1) {
        w2 += __shfl_xor(w2, off);
        w3 += __shfl_xor(w3, off);
    }
    float m = fmaxf(w2, w3);
    float x2 = __expf(w2 - m), x3 = __expf(w3 - m);
    float inv = 1.0f / (x2 + x3);
    float s2 = x2 * inv, s3 = x3 * inv;
    float4 o;
    o.x = s2 * a2.x + s3 * a3.x; o.y = s2 * a2.y + s3 * a3.y;
    o.z = s2 * a2.z + s3 * a3.z; o.w = s2 * a2.w + s3 * a3.w;
    ((float4*)mixed)[o4] = o;
    if (l16 == 0) { score[(size_t)i * 2] = s2; score[(size_t)i * 2 + 1] = s3; }
}

// v[k] = sum_j att_m[k][j] * att[j]
__global__ void vvec_kernel(const float* __restrict__ att_m, const float* __restrict__ att,
                            float* __restrict__ v) {
    int k = threadIdx.x;
    float s = 0.0f;
    for (int j = 0; j < 64; ++j) s += att_m[k * 64 + j] * att[j];
    v[k] = s;
}

extern "C" void kernel_launch(void* const* d_in, const int* in_sizes, int n_in,
                              void* d_out, int out_size, void* d_ws, size_t ws_size,
                              hipStream_t stream) {
    const float* user_emb = (const float*)d_in[0];
    const float* W0 = (const float*)d_in[1];
    const float* b0 = (const float*)d_in[2];
    const float* W1 = (const float*)d_in[3];
    const float* b1 = (const float*)d_in[4];
    const float* att = (const float*)d_in[5];
    const float* att_m = (const float*)d_in[6];
    const int* item_rows = (const int*)d_in[7];
    const int* item_cols = (const int*)d_in[8];
    const float* item_vals = (const float*)d_in[9];
    const int* user_rows = (const int*)d_in[10];
    const int* user_cols = (const int*)d_in[11];
    const float* user_vals = (const float*)d_in[12];

    float* out = (float*)d_out;
    float* mixed = out;                          // N*64, doubles as acc2
    float* score = out + (size_t)N_NODE * 64;

    // all region sizes multiple of 256B -> float4/int2 alignment everywhere
    char* w = (char*)d_ws;
    float* acc3 = (float*)w;   w += (size_t)N_NODE * 64 * 4;
    float* u_cur = (float*)w;  w += (size_t)N_NODE * 64 * 4;
    float* u_nxt = (float*)w;  w += (size_t)N_NODE * 64 * 4;
    int* row_ptr = (int*)w;    w += ((size_t)NROWS_TOTAL + 64) * 4;
    int* fill = (int*)w;       w += ((size_t)NROWS_TOTAL + 64) * 4;
    int2* ecv = (int2*)w;      w += (size_t)TOT_E * 8;
    float* vvec = (float*)w;   w += 256;
    int* bsum = (int*)w;       w += 2048;
    int* boff = (int*)w;       w += 2048;

    const int NB4 = (N_NODE + 3) / 4;
    const int NB16 = (N_NODE + 15) / 16;
    const int EB2 = (TOT_E + 255) / 256;
    const int* rp_item = row_ptr;
    const int* rp_user = row_ptr + N_NODE;

    // CSR build (both graphs in one indexing space)
    hipMemsetAsync(fill, 0, (size_t)NROWS_TOTAL * 4, stream);
    hist2_kernel<<<EB2, 256, 0, stream>>>(item_rows, user_rows, fill);
    scan1_kernel<<<SCAN_BLOCKS, 256, 0, stream>>>(fill, bsum, NROWS_TOTAL);
    scan2_kernel<<<1, 512, 0, stream>>>(bsum, boff);
    scan3_kernel<<<SCAN_BLOCKS, 256, 0, stream>>>(fill, boff, row_ptr, fill, NROWS_TOTAL);
    scatterP_kernel<<<2048, 256, 0, stream>>>(item_rows, item_cols, item_vals,
                                              user_rows, user_cols, user_vals, fill, ecv);
    vvec_kernel<<<1, 64, 0, stream>>>(att_m, att, vvec);

    // channel 2: item graph, acc lives in d_out (mixed region)
    gate_kernel<<<NB4, 256, 0, stream>>>(user_emb, W0, b0, mixed, u_cur, N_NODE);
    spmm_norm_acc<true><<<NB16, 256, 0, stream>>>(rp_item, ecv, u_cur, u_nxt, mixed, N_NODE);
    spmm_norm_acc<true><<<NB16, 256, 0, stream>>>(rp_item, ecv, u_nxt, u_cur, mixed, N_NODE);
    spmm_norm_acc<false><<<NB16, 256, 0, stream>>>(rp_item, ecv, u_cur, nullptr, mixed, N_NODE);

    // channel 3: user graph
    gate_kernel<<<NB4, 256, 0, stream>>>(user_emb, W1, b1, acc3, u_cur, N_NODE);
    spmm_norm_acc<true><<<NB16, 256, 0, stream>>>(rp_user, ecv, u_cur, u_nxt, acc3, N_NODE);
    spmm_norm_acc<true><<<NB16, 256, 0, stream>>>(rp_user, ecv, u_nxt, u_cur, acc3, N_NODE);
    spmm_norm_mix<<<NB16, 256, 0, stream>>>(rp_user, ecv, u_cur, acc3, mixed, vvec, score, N_NODE);
}

// Round 6
// 921.147 us; speedup vs baseline: 1.8641x; 1.2458x over previous
//
#include <hip/hip_runtime.h>

#define N_NODE 200000
#define EMB 64
#define N_EDGES 2000000
#define NROWS_TOTAL (2 * N_NODE)        // both graphs' rows concatenated
#define TOT_E (2 * N_EDGES)

// counting-sort geometry
#define BSHIFT 10
#define BROWS 1024                                   // rows per bucket
#define NBUCK ((NROWS_TOTAL + BROWS - 1) / BROWS)    // 391
#define NB 512                                       // binning blocks
#define CHUNK ((TOT_E + NB - 1) / NB)                // 7813 edges per block
#define SCAN_N (NBUCK * NB)                          // 200192
#define SCAN_CHUNK 1024
#define SCAN_BLOCKS ((SCAN_N + SCAN_CHUNK - 1) / SCAN_CHUNK)  // 196

// out = emb * sigmoid(emb @ W + b), written to two destinations (acc init + u_cur)
__global__ void gate_kernel(const float* __restrict__ emb,
                            const float* __restrict__ W,
                            const float* __restrict__ b,
                            float* __restrict__ out1,
                            float* __restrict__ out2, int n) {
    __shared__ float Wl[64 * 64];
    __shared__ float rowbuf[4][64];
    int t = threadIdx.x;
    for (int k = t; k < 4096; k += 256) Wl[k] = W[k];
    int nl = t >> 6, j = t & 63;
    int i = blockIdx.x * 4 + nl;
    if (i < n) rowbuf[nl][j] = emb[(size_t)i * 64 + j];
    __syncthreads();
    if (i >= n) return;
    float s = b[j];
#pragma unroll
    for (int k = 0; k < 64; ++k) s += rowbuf[nl][k] * Wl[k * 64 + j];
    float g = 1.0f / (1.0f + __expf(-s));
    float val = rowbuf[nl][j] * g;
    out1[(size_t)i * 64 + j] = val;
    out2[(size_t)i * 64 + j] = val;
}

// phase 1: per-block LDS bucket histogram -> bc[bucket*NB + blk]
__global__ void binA_kernel(const int* __restrict__ item_rows,
                            const int* __restrict__ user_rows,
                            int* __restrict__ bc) {
    __shared__ int h[NBUCK];
    int t = threadIdx.x, blk = blockIdx.x;
    for (int k = t; k < NBUCK; k += 256) h[k] = 0;
    __syncthreads();
    int lo = blk * CHUNK, hi = min(lo + CHUNK, TOT_E);
    for (int i = lo + t; i < hi; i += 256) {
        int g = (i < N_EDGES) ? item_rows[i] : (N_NODE + user_rows[i - N_EDGES]);
        atomicAdd(&h[g >> BSHIFT], 1);
    }
    __syncthreads();
    for (int k = t; k < NBUCK; k += 256) bc[k * NB + blk] = h[k];
}

// ---- generic device-wide exclusive scan over SCAN_N ints ----
__global__ void scan1_kernel(const int* __restrict__ cnt, int* __restrict__ bsum, int n) {
    int t = threadIdx.x;
    int base = blockIdx.x * SCAN_CHUNK + t * 4;
    int s = 0;
#pragma unroll
    for (int k = 0; k < 4; ++k) {
        int i = base + k;
        if (i < n) s += cnt[i];
    }
#pragma unroll
    for (int off = 32; off; off >>= 1) s += __shfl_xor(s, off);
    __shared__ int ws[4];
    int lane = t & 63, w = t >> 6;
    if (lane == 0) ws[w] = s;
    __syncthreads();
    if (t == 0) bsum[blockIdx.x] = ws[0] + ws[1] + ws[2] + ws[3];
}

__global__ void scan2_kernel(const int* __restrict__ bsum, int* __restrict__ boff, int nblocks) {
    __shared__ int sh[256];
    int t = threadIdx.x;
    int v = (t < nblocks) ? bsum[t] : 0;
    sh[t] = v;
    __syncthreads();
    for (int off = 1; off < 256; off <<= 1) {
        int u = (t >= off) ? sh[t - off] : 0;
        __syncthreads();
        sh[t] += u;
        __syncthreads();
    }
    if (t < nblocks) boff[t] = sh[t] - v;   // exclusive
}

__global__ void scan3_kernel(const int* __restrict__ cnt, const int* __restrict__ boff,
                             int* __restrict__ out, int n) {
    int t = threadIdx.x;
    int lane = t & 63, w = t >> 6;
    int base = blockIdx.x * SCAN_CHUNK + t * 4;
    int c[4];
#pragma unroll
    for (int k = 0; k < 4; ++k) {
        int i = base + k;
        c[k] = (i < n) ? cnt[i] : 0;
    }
    int e1 = c[0], e2 = c[0] + c[1], e3 = c[0] + c[1] + c[2];
    int tsum = e3 + c[3];
    int incl = tsum;
#pragma unroll
    for (int off = 1; off < 64; off <<= 1) {
        int u = __shfl_up(incl, off);
        if (lane >= off) incl += u;
    }
    int excl = incl - tsum;
    __shared__ int wsum[4];
    if (lane == 63) wsum[w] = incl;
    __syncthreads();
    int woff = 0;
    for (int k = 0; k < 4; ++k) if (k < w) woff += wsum[k];
    int g = boff[blockIdx.x] + woff + excl;
    int vv[4] = {g, g + e1, g + e2, g + e3};
#pragma unroll
    for (int k = 0; k < 4; ++k) {
        int i = base + k;
        if (i < n) out[i] = vv[k];
    }
}

// phase 2: stage edges into (bucket, block)-contiguous ranges; LDS cursors, no global atomics
__global__ void binB_kernel(const int* __restrict__ item_rows, const int* __restrict__ item_cols,
                            const float* __restrict__ item_vals,
                            const int* __restrict__ user_rows, const int* __restrict__ user_cols,
                            const float* __restrict__ user_vals,
                            const int* __restrict__ soff, int2* __restrict__ staged) {
    __shared__ int cur[NBUCK];
    int t = threadIdx.x, blk = blockIdx.x;
    for (int k = t; k < NBUCK; k += 256) cur[k] = soff[k * NB + blk];
    __syncthreads();
    int lo = blk * CHUNK, hi = min(lo + CHUNK, TOT_E);
    for (int i = lo + t; i < hi; i += 256) {
        int g, c; float v;
        if (i < N_EDGES) { g = item_rows[i]; c = item_cols[i]; v = item_vals[i]; }
        else { int j = i - N_EDGES; g = N_NODE + user_rows[j]; c = user_cols[j]; v = user_vals[j]; }
        int pos = atomicAdd(&cur[g >> BSHIFT], 1);
        staged[pos] = make_int2(((g & (BROWS - 1)) << 18) | c, __float_as_int(v));
    }
}

// phase 3: one WG per bucket: LDS row-hist + scan -> row_ptr; local scatter -> ecv
__global__ void finalize_kernel(const int2* __restrict__ staged, const int* __restrict__ soff,
                                int* __restrict__ row_ptr, int2* __restrict__ ecv) {
    __shared__ int hist[BROWS];
    __shared__ int cur[BROWS];
    __shared__ int wsum[4];
    int b = blockIdx.x, t = threadIdx.x;
    int base = soff[b * NB];
    int end = (b + 1 < NBUCK) ? soff[(b + 1) * NB] : TOT_E;
    for (int k = t; k < BROWS; k += 256) hist[k] = 0;
    __syncthreads();
    for (int k = base + t; k < end; k += 256)
        atomicAdd(&hist[staged[k].x >> 18], 1);
    __syncthreads();
    // scan 1024 counts: thread t owns 4 consecutive entries
    int i0 = t * 4;
    int c0 = hist[i0], c1 = hist[i0 + 1], c2 = hist[i0 + 2], c3 = hist[i0 + 3];
    int tsum = c0 + c1 + c2 + c3;
    int lane = t & 63, w = t >> 6;
    int incl = tsum;
#pragma unroll
    for (int off = 1; off < 64; off <<= 1) {
        int u = __shfl_up(incl, off);
        if (lane >= off) incl += u;
    }
    if (lane == 63) wsum[w] = incl;
    __syncthreads();
    int woff = 0;
    for (int k = 0; k < w; ++k) woff += wsum[k];
    int start = base + woff + incl - tsum;
    int g0 = (b << BSHIFT) + i0;
    int s0 = start, s1 = start + c0, s2 = s1 + c1, s3 = s2 + c2;
    if (g0 + 0 < NROWS_TOTAL) row_ptr[g0 + 0] = s0;
    if (g0 + 1 < NROWS_TOTAL) row_ptr[g0 + 1] = s1;
    if (g0 + 2 < NROWS_TOTAL) row_ptr[g0 + 2] = s2;
    if (g0 + 3 < NROWS_TOTAL) row_ptr[g0 + 3] = s3;
    cur[i0] = s0; cur[i0 + 1] = s1; cur[i0 + 2] = s2; cur[i0 + 3] = s3;
    if (b == 0 && t == 0) row_ptr[NROWS_TOTAL] = TOT_E;
    __syncthreads();
    for (int k = base + t; k < end; k += 256) {
        int2 p = staged[k];
        int gl = p.x >> 18;
        int pos = atomicAdd(&cur[gl], 1);
        ecv[pos] = make_int2(p.x & 0x3FFFF, p.y);
    }
}

// 16 lanes per row, 4 rows per wave, float4 per lane.
template <bool WRITE_Y>
__global__ void spmm_norm_acc(const int* __restrict__ row_ptr, const int2* __restrict__ ecv,
                              const float* __restrict__ x,
                              float* __restrict__ y, float* __restrict__ acc, int n) {
    int t = threadIdx.x;
    int lane = t & 63;
    int sub = lane >> 4;
    int l16 = lane & 15;
    int i = blockIdx.x * 16 + (t >> 6) * 4 + sub;
    if (i >= n) return;
    int s = row_ptr[i], e = row_ptr[i + 1];
    const float4* x4 = (const float4*)x;
    float4 a = make_float4(0.f, 0.f, 0.f, 0.f);
    int gbase = sub * 16;
    for (int base = s; base < e; base += 16) {
        int idx = base + l16;
        int cl = 0; float vl = 0.0f;
        if (idx < e) { int2 p = ecv[idx]; cl = p.x; vl = __int_as_float(p.y); }
        int cnt = min(16, e - base);
        int cnt4 = (cnt + 3) & ~3;
        for (int k = 0; k < cnt4; k += 4) {
#pragma unroll
            for (int u = 0; u < 4; ++u) {
                int c = __shfl(cl, gbase + k + u);
                float v = __shfl(vl, gbase + k + u);
                float4 xv = x4[(size_t)c * 16 + l16];
                a.x += v * xv.x; a.y += v * xv.y; a.z += v * xv.z; a.w += v * xv.w;
            }
        }
    }
    size_t o4 = (size_t)i * 16 + l16;
    if (WRITE_Y) ((float4*)y)[o4] = a;
    float sq = a.x * a.x + a.y * a.y + a.z * a.z + a.w * a.w;
#pragma unroll
    for (int off = 8; off; off >>= 1) sq += __shfl_xor(sq, off);
    float rinv = 1.0f / fmaxf(sqrtf(sq), 1e-12f);
    float4* acc4 = (float4*)acc;
    float4 aa = acc4[o4];
    aa.x += a.x * rinv; aa.y += a.y * rinv; aa.z += a.z * rinv; aa.w += a.w * rinv;
    acc4[o4] = aa;
}

// channel-3 last layer fused with channel attention + mix
__global__ void spmm_norm_mix(const int* __restrict__ row_ptr, const int2* __restrict__ ecv,
                              const float* __restrict__ x, const float* __restrict__ acc3,
                              float* __restrict__ mixed, const float* __restrict__ vvec,
                              float* __restrict__ score, int n) {
    int t = threadIdx.x;
    int lane = t & 63;
    int sub = lane >> 4;
    int l16 = lane & 15;
    int i = blockIdx.x * 16 + (t >> 6) * 4 + sub;
    if (i >= n) return;
    int s = row_ptr[i], e = row_ptr[i + 1];
    const float4* x4 = (const float4*)x;
    float4 a = make_float4(0.f, 0.f, 0.f, 0.f);
    int gbase = sub * 16;
    for (int base = s; base < e; base += 16) {
        int idx = base + l16;
        int cl = 0; float vl = 0.0f;
        if (idx < e) { int2 p = ecv[idx]; cl = p.x; vl = __int_as_float(p.y); }
        int cnt = min(16, e - base);
        int cnt4 = (cnt + 3) & ~3;
        for (int k = 0; k < cnt4; k += 4) {
#pragma unroll
            for (int u = 0; u < 4; ++u) {
                int c = __shfl(cl, gbase + k + u);
                float v = __shfl(vl, gbase + k + u);
                float4 xv = x4[(size_t)c * 16 + l16];
                a.x += v * xv.x; a.y += v * xv.y; a.z += v * xv.z; a.w += v * xv.w;
            }
        }
    }
    float sq = a.x * a.x + a.y * a.y + a.z * a.z + a.w * a.w;
#pragma unroll
    for (int off = 8; off; off >>= 1) sq += __shfl_xor(sq, off);
    float rinv = 1.0f / fmaxf(sqrtf(sq), 1e-12f);
    size_t o4 = (size_t)i * 16 + l16;
    float4 a3 = ((const float4*)acc3)[o4];
    a3.x += a.x * rinv; a3.y += a.y * rinv; a3.z += a.z * rinv; a3.w += a.w * rinv;
    float4 a2 = ((float4*)mixed)[o4];
    float4 vv = ((const float4*)vvec)[l16];
    float w2 = a2.x * vv.x + a2.y * vv.y + a2.z * vv.z + a2.w * vv.w;
    float w3 = a3.x * vv.x + a3.y * vv.y + a3.z * vv.z + a3.w * vv.w;
#pragma unroll
    for (int off = 8; off; off >>= 1) {
        w2 += __shfl_xor(w2, off);
        w3 += __shfl_xor(w3, off);
    }
    float m = fmaxf(w2, w3);
    float x2 = __expf(w2 - m), x3 = __expf(w3 - m);
    float inv = 1.0f / (x2 + x3);
    float s2 = x2 * inv, s3 = x3 * inv;
    float4 o;
    o.x = s2 * a2.x + s3 * a3.x; o.y = s2 * a2.y + s3 * a3.y;
    o.z = s2 * a2.z + s3 * a3.z; o.w = s2 * a2.w + s3 * a3.w;
    ((float4*)mixed)[o4] = o;
    if (l16 == 0) { score[(size_t)i * 2] = s2; score[(size_t)i * 2 + 1] = s3; }
}

// v[k] = sum_j att_m[k][j] * att[j]
__global__ void vvec_kernel(const float* __restrict__ att_m, const float* __restrict__ att,
                            float* __restrict__ v) {
    int k = threadIdx.x;
    float s = 0.0f;
    for (int j = 0; j < 64; ++j) s += att_m[k * 64 + j] * att[j];
    v[k] = s;
}

extern "C" void kernel_launch(void* const* d_in, const int* in_sizes, int n_in,
                              void* d_out, int out_size, void* d_ws, size_t ws_size,
                              hipStream_t stream) {
    const float* user_emb = (const float*)d_in[0];
    const float* W0 = (const float*)d_in[1];
    const float* b0 = (const float*)d_in[2];
    const float* W1 = (const float*)d_in[3];
    const float* b1 = (const float*)d_in[4];
    const float* att = (const float*)d_in[5];
    const float* att_m = (const float*)d_in[6];
    const int* item_rows = (const int*)d_in[7];
    const int* item_cols = (const int*)d_in[8];
    const float* item_vals = (const float*)d_in[9];
    const int* user_rows = (const int*)d_in[10];
    const int* user_cols = (const int*)d_in[11];
    const float* user_vals = (const float*)d_in[12];

    float* out = (float*)d_out;
    float* mixed = out;                          // N*64, doubles as acc2
    float* score = out + (size_t)N_NODE * 64;

    char* w = (char*)d_ws;
    float* acc3 = (float*)w;   w += (size_t)N_NODE * 64 * 4;
    float* u_cur = (float*)w;  w += (size_t)N_NODE * 64 * 4;
    float* u_nxt = (float*)w;  w += (size_t)N_NODE * 64 * 4;   // staged overlays this during build
    int* row_ptr = (int*)w;    w += ((size_t)NROWS_TOTAL + 64) * 4;
    int2* ecv = (int2*)w;      w += (size_t)TOT_E * 8;
    float* vvec = (float*)w;   w += 256;
    int* bc = (int*)w;         w += (size_t)SCAN_N * 4;        // per-(bucket,block) counts
    int* soff = (int*)w;       w += (size_t)SCAN_N * 4;        // scanned offsets
    int* bsum = (int*)w;       w += 1024;
    int* boff = (int*)w;       w += 1024;
    int2* staged = (int2*)u_nxt;                // 32MB <= 51.2MB, dead before propagate

    const int NB4 = (N_NODE + 3) / 4;
    const int NB16 = (N_NODE + 15) / 16;
    const int* rp_item = row_ptr;
    const int* rp_user = row_ptr + N_NODE;

    // counting-sort CSR build (both graphs in one indexing space), no global atomics
    binA_kernel<<<NB, 256, 0, stream>>>(item_rows, user_rows, bc);
    scan1_kernel<<<SCAN_BLOCKS, 256, 0, stream>>>(bc, bsum, SCAN_N);
    scan2_kernel<<<1, 256, 0, stream>>>(bsum, boff, SCAN_BLOCKS);
    scan3_kernel<<<SCAN_BLOCKS, 256, 0, stream>>>(bc, boff, soff, SCAN_N);
    binB_kernel<<<NB, 256, 0, stream>>>(item_rows, item_cols, item_vals,
                                        user_rows, user_cols, user_vals, soff, staged);
    finalize_kernel<<<NBUCK, 256, 0, stream>>>(staged, soff, row_ptr, ecv);
    vvec_kernel<<<1, 64, 0, stream>>>(att_m, att, vvec);

    // channel 2: item graph, acc lives in d_out (mixed region)
    gate_kernel<<<NB4, 256, 0, stream>>>(user_emb, W0, b0, mixed, u_cur, N_NODE);
    spmm_norm_acc<true><<<NB16, 256, 0, stream>>>(rp_item, ecv, u_cur, u_nxt, mixed, N_NODE);
    spmm_norm_acc<true><<<NB16, 256, 0, stream>>>(rp_item, ecv, u_nxt, u_cur, mixed, N_NODE);
    spmm_norm_acc<false><<<NB16, 256, 0, stream>>>(rp_item, ecv, u_cur, nullptr, mixed, N_NODE);

    // channel 3: user graph
    gate_kernel<<<NB4, 256, 0, stream>>>(user_emb, W1, b1, acc3, u_cur, N_NODE);
    spmm_norm_acc<true><<<NB16, 256, 0, stream>>>(rp_user, ecv, u_cur, u_nxt, acc3, N_NODE);
    spmm_norm_acc<true><<<NB16, 256, 0, stream>>>(rp_user, ecv, u_nxt, u_cur, acc3, N_NODE);
    spmm_norm_mix<<<NB16, 256, 0, stream>>>(rp_user, ecv, u_cur, acc3, mixed, vvec, score, N_NODE);
}

// Round 7
// 785.896 us; speedup vs baseline: 2.1849x; 1.1721x over previous
//
#include <hip/hip_runtime.h>

#define N_NODE 200000
#define EMB 64
#define N_EDGES 2000000
#define NROWS_TOTAL (2 * N_NODE)        // both graphs' rows concatenated
#define TOT_E (2 * N_EDGES)

// counting-sort geometry
#define BSHIFT 10
#define BROWS 1024                                   // rows per bucket
#define NBUCK ((NROWS_TOTAL + BROWS - 1) / BROWS)    // 391
#define NB 512                                       // binning blocks
#define CHUNK ((TOT_E + NB - 1) / NB)                // 7813 edges per block
#define SCAN_N (NBUCK * NB)                          // 200192
#define SCAN_CHUNK 1024
#define SCAN_BLOCKS ((SCAN_N + SCAN_CHUNK - 1) / SCAN_CHUNK)  // 196

#define GATE_NPB 64                                  // nodes per gate block (200000/64 = 3125 exact)

// out = emb * sigmoid(emb @ W + b). 16 lanes/node, float4/lane: 1 b32 + 1 b128 DS read per k-step
// serves 4 nodes -> ~4x fewer DS-pipe ops than scalar version (was LDS-issue-bound).
__global__ void gate_kernel(const float* __restrict__ emb,
                            const float* __restrict__ W,
                            const float* __restrict__ b,
                            float* __restrict__ out1,
                            float* __restrict__ out2) {
    __shared__ float4 Wl4[64][16];
    __shared__ float4 bl4[16];
    __shared__ float rowbuf[4][4][72];   // [wave][sub][72] 72-pad: banks differ per sub; 288B keeps f4 align
    int t = threadIdx.x;
    const float4* Wg4 = (const float4*)W;
    for (int idx = t; idx < 1024; idx += 256) Wl4[idx >> 4][idx & 15] = Wg4[idx];
    if (t < 16) bl4[t] = ((const float4*)b)[t];
    __syncthreads();
    int w = t >> 6, lane = t & 63, sub = lane >> 4, l16 = lane & 15;
    int base = blockIdx.x * GATE_NPB + w * 4;
    const float4* emb4 = (const float4*)emb;
#pragma unroll 1
    for (int it = 0; it < GATE_NPB / 16; ++it, base += 16) {
        int i = base + sub;
        float4 xr = emb4[(size_t)i * 16 + l16];
        *(float4*)&rowbuf[w][sub][l16 * 4] = xr;
        __syncthreads();
        float4 s = bl4[l16];
#pragma unroll 16
        for (int k = 0; k < 64; ++k) {
            float xk = rowbuf[w][sub][k];
            float4 wv = Wl4[k][l16];
            s.x += xk * wv.x; s.y += xk * wv.y; s.z += xk * wv.z; s.w += xk * wv.w;
        }
        float4 g;
        g.x = 1.0f / (1.0f + __expf(-s.x));
        g.y = 1.0f / (1.0f + __expf(-s.y));
        g.z = 1.0f / (1.0f + __expf(-s.z));
        g.w = 1.0f / (1.0f + __expf(-s.w));
        float4 val;
        val.x = xr.x * g.x; val.y = xr.y * g.y; val.z = xr.z * g.z; val.w = xr.w * g.w;
        size_t o4 = (size_t)i * 16 + l16;
        ((float4*)out1)[o4] = val;
        ((float4*)out2)[o4] = val;
        __syncthreads();
    }
}

// phase 1: per-block LDS bucket histogram -> bc[bucket*NB + blk]
__global__ void binA_kernel(const int* __restrict__ item_rows,
                            const int* __restrict__ user_rows,
                            int* __restrict__ bc) {
    __shared__ int h[NBUCK];
    int t = threadIdx.x, blk = blockIdx.x;
    for (int k = t; k < NBUCK; k += 256) h[k] = 0;
    __syncthreads();
    int lo = blk * CHUNK, hi = min(lo + CHUNK, TOT_E);
    for (int i = lo + t; i < hi; i += 256) {
        int g = (i < N_EDGES) ? item_rows[i] : (N_NODE + user_rows[i - N_EDGES]);
        atomicAdd(&h[g >> BSHIFT], 1);
    }
    __syncthreads();
    for (int k = t; k < NBUCK; k += 256) bc[k * NB + blk] = h[k];
}

// ---- generic device-wide exclusive scan over SCAN_N ints ----
__global__ void scan1_kernel(const int* __restrict__ cnt, int* __restrict__ bsum, int n) {
    int t = threadIdx.x;
    int base = blockIdx.x * SCAN_CHUNK + t * 4;
    int s = 0;
#pragma unroll
    for (int k = 0; k < 4; ++k) {
        int i = base + k;
        if (i < n) s += cnt[i];
    }
#pragma unroll
    for (int off = 32; off; off >>= 1) s += __shfl_xor(s, off);
    __shared__ int ws[4];
    int lane = t & 63, w = t >> 6;
    if (lane == 0) ws[w] = s;
    __syncthreads();
    if (t == 0) bsum[blockIdx.x] = ws[0] + ws[1] + ws[2] + ws[3];
}

__global__ void scan2_kernel(const int* __restrict__ bsum, int* __restrict__ boff, int nblocks) {
    __shared__ int sh[256];
    int t = threadIdx.x;
    int v = (t < nblocks) ? bsum[t] : 0;
    sh[t] = v;
    __syncthreads();
    for (int off = 1; off < 256; off <<= 1) {
        int u = (t >= off) ? sh[t - off] : 0;
        __syncthreads();
        sh[t] += u;
        __syncthreads();
    }
    if (t < nblocks) boff[t] = sh[t] - v;   // exclusive
}

__global__ void scan3_kernel(const int* __restrict__ cnt, const int* __restrict__ boff,
                             int* __restrict__ out, int n) {
    int t = threadIdx.x;
    int lane = t & 63, w = t >> 6;
    int base = blockIdx.x * SCAN_CHUNK + t * 4;
    int c[4];
#pragma unroll
    for (int k = 0; k < 4; ++k) {
        int i = base + k;
        c[k] = (i < n) ? cnt[i] : 0;
    }
    int e1 = c[0], e2 = c[0] + c[1], e3 = c[0] + c[1] + c[2];
    int tsum = e3 + c[3];
    int incl = tsum;
#pragma unroll
    for (int off = 1; off < 64; off <<= 1) {
        int u = __shfl_up(incl, off);
        if (lane >= off) incl += u;
    }
    int excl = incl - tsum;
    __shared__ int wsum[4];
    if (lane == 63) wsum[w] = incl;
    __syncthreads();
    int woff = 0;
    for (int k = 0; k < 4; ++k) if (k < w) woff += wsum[k];
    int g = boff[blockIdx.x] + woff + excl;
    int vv[4] = {g, g + e1, g + e2, g + e3};
#pragma unroll
    for (int k = 0; k < 4; ++k) {
        int i = base + k;
        if (i < n) out[i] = vv[k];
    }
}

// phase 2: stage edges into (bucket, block)-contiguous ranges; LDS cursors, no global atomics
__global__ void binB_kernel(const int* __restrict__ item_rows, const int* __restrict__ item_cols,
                            const float* __restrict__ item_vals,
                            const int* __restrict__ user_rows, const int* __restrict__ user_cols,
                            const float* __restrict__ user_vals,
                            const int* __restrict__ soff, int2* __restrict__ staged) {
    __shared__ int cur[NBUCK];
    int t = threadIdx.x, blk = blockIdx.x;
    for (int k = t; k < NBUCK; k += 256) cur[k] = soff[k * NB + blk];
    __syncthreads();
    int lo = blk * CHUNK, hi = min(lo + CHUNK, TOT_E);
    for (int i = lo + t; i < hi; i += 256) {
        int g, c; float v;
        if (i < N_EDGES) { g = item_rows[i]; c = item_cols[i]; v = item_vals[i]; }
        else { int j = i - N_EDGES; g = N_NODE + user_rows[j]; c = user_cols[j]; v = user_vals[j]; }
        int pos = atomicAdd(&cur[g >> BSHIFT], 1);
        staged[pos] = make_int2(((g & (BROWS - 1)) << 18) | c, __float_as_int(v));
    }
}

// phase 3: one WG per bucket: LDS row-hist + scan -> row_ptr; local scatter -> ecv
__global__ void finalize_kernel(const int2* __restrict__ staged, const int* __restrict__ soff,
                                int* __restrict__ row_ptr, int2* __restrict__ ecv) {
    __shared__ int hist[BROWS];
    __shared__ int cur[BROWS];
    __shared__ int wsum[4];
    int b = blockIdx.x, t = threadIdx.x;
    int base = soff[b * NB];
    int end = (b + 1 < NBUCK) ? soff[(b + 1) * NB] : TOT_E;
    for (int k = t; k < BROWS; k += 256) hist[k] = 0;
    __syncthreads();
    for (int k = base + t; k < end; k += 256)
        atomicAdd(&hist[staged[k].x >> 18], 1);
    __syncthreads();
    // scan 1024 counts: thread t owns 4 consecutive entries
    int i0 = t * 4;
    int c0 = hist[i0], c1 = hist[i0 + 1], c2 = hist[i0 + 2], c3 = hist[i0 + 3];
    int tsum = c0 + c1 + c2 + c3;
    int lane = t & 63, w = t >> 6;
    int incl = tsum;
#pragma unroll
    for (int off = 1; off < 64; off <<= 1) {
        int u = __shfl_up(incl, off);
        if (lane >= off) incl += u;
    }
    if (lane == 63) wsum[w] = incl;
    __syncthreads();
    int woff = 0;
    for (int k = 0; k < w; ++k) woff += wsum[k];
    int start = base + woff + incl - tsum;
    int g0 = (b << BSHIFT) + i0;
    int s0 = start, s1 = start + c0, s2 = s1 + c1, s3 = s2 + c2;
    if (g0 + 0 < NROWS_TOTAL) row_ptr[g0 + 0] = s0;
    if (g0 + 1 < NROWS_TOTAL) row_ptr[g0 + 1] = s1;
    if (g0 + 2 < NROWS_TOTAL) row_ptr[g0 + 2] = s2;
    if (g0 + 3 < NROWS_TOTAL) row_ptr[g0 + 3] = s3;
    cur[i0] = s0; cur[i0 + 1] = s1; cur[i0 + 2] = s2; cur[i0 + 3] = s3;
    if (b == 0 && t == 0) row_ptr[NROWS_TOTAL] = TOT_E;
    __syncthreads();
    for (int k = base + t; k < end; k += 256) {
        int2 p = staged[k];
        int gl = p.x >> 18;
        int pos = atomicAdd(&cur[gl], 1);
        ecv[pos] = make_int2(p.x & 0x3FFFF, p.y);
    }
}

// 16 lanes per row, 4 rows per wave, float4 per lane.
template <bool WRITE_Y>
__global__ void spmm_norm_acc(const int* __restrict__ row_ptr, const int2* __restrict__ ecv,
                              const float* __restrict__ x,
                              float* __restrict__ y, float* __restrict__ acc, int n) {
    int t = threadIdx.x;
    int lane = t & 63;
    int sub = lane >> 4;
    int l16 = lane & 15;
    int i = blockIdx.x * 16 + (t >> 6) * 4 + sub;
    if (i >= n) return;
    int s = row_ptr[i], e = row_ptr[i + 1];
    const float4* x4 = (const float4*)x;
    float4 a = make_float4(0.f, 0.f, 0.f, 0.f);
    int gbase = sub * 16;
    for (int base = s; base < e; base += 16) {
        int idx = base + l16;
        int cl = 0; float vl = 0.0f;
        if (idx < e) { int2 p = ecv[idx]; cl = p.x; vl = __int_as_float(p.y); }
        int cnt = min(16, e - base);
        int cnt4 = (cnt + 3) & ~3;
        for (int k = 0; k < cnt4; k += 4) {
#pragma unroll
            for (int u = 0; u < 4; ++u) {
                int c = __shfl(cl, gbase + k + u);
                float v = __shfl(vl, gbase + k + u);
                float4 xv = x4[(size_t)c * 16 + l16];
                a.x += v * xv.x; a.y += v * xv.y; a.z += v * xv.z; a.w += v * xv.w;
            }
        }
    }
    size_t o4 = (size_t)i * 16 + l16;
    if (WRITE_Y) ((float4*)y)[o4] = a;
    float sq = a.x * a.x + a.y * a.y + a.z * a.z + a.w * a.w;
#pragma unroll
    for (int off = 8; off; off >>= 1) sq += __shfl_xor(sq, off);
    float rinv = 1.0f / fmaxf(sqrtf(sq), 1e-12f);
    float4* acc4 = (float4*)acc;
    float4 aa = acc4[o4];
    aa.x += a.x * rinv; aa.y += a.y * rinv; aa.z += a.z * rinv; aa.w += a.w * rinv;
    acc4[o4] = aa;
}

// channel-3 last layer fused with channel attention + mix
__global__ void spmm_norm_mix(const int* __restrict__ row_ptr, const int2* __restrict__ ecv,
                              const float* __restrict__ x, const float* __restrict__ acc3,
                              float* __restrict__ mixed, const float* __restrict__ vvec,
                              float* __restrict__ score, int n) {
    int t = threadIdx.x;
    int lane = t & 63;
    int sub = lane >> 4;
    int l16 = lane & 15;
    int i = blockIdx.x * 16 + (t >> 6) * 4 + sub;
    if (i >= n) return;
    int s = row_ptr[i], e = row_ptr[i + 1];
    const float4* x4 = (const float4*)x;
    float4 a = make_float4(0.f, 0.f, 0.f, 0.f);
    int gbase = sub * 16;
    for (int base = s; base < e; base += 16) {
        int idx = base + l16;
        int cl = 0; float vl = 0.0f;
        if (idx < e) { int2 p = ecv[idx]; cl = p.x; vl = __int_as_float(p.y); }
        int cnt = min(16, e - base);
        int cnt4 = (cnt + 3) & ~3;
        for (int k = 0; k < cnt4; k += 4) {
#pragma unroll
            for (int u = 0; u < 4; ++u) {
                int c = __shfl(cl, gbase + k + u);
                float v = __shfl(vl, gbase + k + u);
                float4 xv = x4[(size_t)c * 16 + l16];
                a.x += v * xv.x; a.y += v * xv.y; a.z += v * xv.z; a.w += v * xv.w;
            }
        }
    }
    float sq = a.x * a.x + a.y * a.y + a.z * a.z + a.w * a.w;
#pragma unroll
    for (int off = 8; off; off >>= 1) sq += __shfl_xor(sq, off);
    float rinv = 1.0f / fmaxf(sqrtf(sq), 1e-12f);
    size_t o4 = (size_t)i * 16 + l16;
    float4 a3 = ((const float4*)acc3)[o4];
    a3.x += a.x * rinv; a3.y += a.y * rinv; a3.z += a.z * rinv; a3.w += a.w * rinv;
    float4 a2 = ((float4*)mixed)[o4];
    float4 vv = ((const float4*)vvec)[l16];
    float w2 = a2.x * vv.x + a2.y * vv.y + a2.z * vv.z + a2.w * vv.w;
    float w3 = a3.x * vv.x + a3.y * vv.y + a3.z * vv.z + a3.w * vv.w;
#pragma unroll
    for (int off = 8; off; off >>= 1) {
        w2 += __shfl_xor(w2, off);
        w3 += __shfl_xor(w3, off);
    }
    float m = fmaxf(w2, w3);
    float x2 = __expf(w2 - m), x3 = __expf(w3 - m);
    float inv = 1.0f / (x2 + x3);
    float s2 = x2 * inv, s3 = x3 * inv;
    float4 o;
    o.x = s2 * a2.x + s3 * a3.x; o.y = s2 * a2.y + s3 * a3.y;
    o.z = s2 * a2.z + s3 * a3.z; o.w = s2 * a2.w + s3 * a3.w;
    ((float4*)mixed)[o4] = o;
    if (l16 == 0) { score[(size_t)i * 2] = s2; score[(size_t)i * 2 + 1] = s3; }
}

// v[k] = sum_j att_m[k][j] * att[j]
__global__ void vvec_kernel(const float* __restrict__ att_m, const float* __restrict__ att,
                            float* __restrict__ v) {
    int k = threadIdx.x;
    float s = 0.0f;
    for (int j = 0; j < 64; ++j) s += att_m[k * 64 + j] * att[j];
    v[k] = s;
}

extern "C" void kernel_launch(void* const* d_in, const int* in_sizes, int n_in,
                              void* d_out, int out_size, void* d_ws, size_t ws_size,
                              hipStream_t stream) {
    const float* user_emb = (const float*)d_in[0];
    const float* W0 = (const float*)d_in[1];
    const float* b0 = (const float*)d_in[2];
    const float* W1 = (const float*)d_in[3];
    const float* b1 = (const float*)d_in[4];
    const float* att = (const float*)d_in[5];
    const float* att_m = (const float*)d_in[6];
    const int* item_rows = (const int*)d_in[7];
    const int* item_cols = (const int*)d_in[8];
    const float* item_vals = (const float*)d_in[9];
    const int* user_rows = (const int*)d_in[10];
    const int* user_cols = (const int*)d_in[11];
    const float* user_vals = (const float*)d_in[12];

    float* out = (float*)d_out;
    float* mixed = out;                          // N*64, doubles as acc2
    float* score = out + (size_t)N_NODE * 64;

    char* w = (char*)d_ws;
    float* acc3 = (float*)w;   w += (size_t)N_NODE * 64 * 4;
    float* u_cur = (float*)w;  w += (size_t)N_NODE * 64 * 4;
    float* u_nxt = (float*)w;  w += (size_t)N_NODE * 64 * 4;   // staged overlays this during build
    int* row_ptr = (int*)w;    w += ((size_t)NROWS_TOTAL + 64) * 4;
    int2* ecv = (int2*)w;      w += (size_t)TOT_E * 8;
    float* vvec = (float*)w;   w += 256;
    int* bc = (int*)w;         w += (size_t)SCAN_N * 4;        // per-(bucket,block) counts
    int* soff = (int*)w;       w += (size_t)SCAN_N * 4;        // scanned offsets
    int* bsum = (int*)w;       w += 1024;
    int* boff = (int*)w;       w += 1024;
    int2* staged = (int2*)u_nxt;                // 32MB <= 51.2MB, dead before propagate

    const int NB16 = (N_NODE + 15) / 16;
    const int GATE_B = N_NODE / GATE_NPB;       // 3125 exact
    const int* rp_item = row_ptr;
    const int* rp_user = row_ptr + N_NODE;

    // counting-sort CSR build (both graphs in one indexing space), no global atomics
    binA_kernel<<<NB, 256, 0, stream>>>(item_rows, user_rows, bc);
    scan1_kernel<<<SCAN_BLOCKS, 256, 0, stream>>>(bc, bsum, SCAN_N);
    scan2_kernel<<<1, 256, 0, stream>>>(bsum, boff, SCAN_BLOCKS);
    scan3_kernel<<<SCAN_BLOCKS, 256, 0, stream>>>(bc, boff, soff, SCAN_N);
    binB_kernel<<<NB, 256, 0, stream>>>(item_rows, item_cols, item_vals,
                                        user_rows, user_cols, user_vals, soff, staged);
    finalize_kernel<<<NBUCK, 256, 0, stream>>>(staged, soff, row_ptr, ecv);
    vvec_kernel<<<1, 64, 0, stream>>>(att_m, att, vvec);

    // channel 2: item graph, acc lives in d_out (mixed region)
    gate_kernel<<<GATE_B, 256, 0, stream>>>(user_emb, W0, b0, mixed, u_cur);
    spmm_norm_acc<true><<<NB16, 256, 0, stream>>>(rp_item, ecv, u_cur, u_nxt, mixed, N_NODE);
    spmm_norm_acc<true><<<NB16, 256, 0, stream>>>(rp_item, ecv, u_nxt, u_cur, mixed, N_NODE);
    spmm_norm_acc<false><<<NB16, 256, 0, stream>>>(rp_item, ecv, u_cur, nullptr, mixed, N_NODE);

    // channel 3: user graph
    gate_kernel<<<GATE_B, 256, 0, stream>>>(user_emb, W1, b1, acc3, u_cur);
    spmm_norm_acc<true><<<NB16, 256, 0, stream>>>(rp_user, ecv, u_cur, u_nxt, acc3, N_NODE);
    spmm_norm_acc<true><<<NB16, 256, 0, stream>>>(rp_user, ecv, u_nxt, u_cur, acc3, N_NODE);
    spmm_norm_mix<<<NB16, 256, 0, stream>>>(rp_user, ecv, u_cur, acc3, mixed, vvec, score, N_NODE);
}

// Round 8
// 563.072 us; speedup vs baseline: 3.0496x; 1.3957x over previous
//
#include <hip/hip_runtime.h>

#define N_NODE 200000
#define EMB 64
#define N_EDGES 2000000
#define NROWS_TOTAL (2 * N_NODE)        // both graphs' rows concatenated
#define TOT_E (2 * N_EDGES)

// counting-sort geometry
#define BSHIFT 10
#define BROWS 1024                                   // rows per bucket
#define NBUCK ((NROWS_TOTAL + BROWS - 1) / BROWS)    // 391
#define NB 512                                       // binning blocks
#define CHUNK ((TOT_E + NB - 1) / NB)                // 7813 edges per block
#define SCAN_N (NBUCK * NB)                          // 200192
#define SCAN_CHUNK 1024
#define SCAN_BLOCKS ((SCAN_N + SCAN_CHUNK - 1) / SCAN_CHUNK)  // 196

#define GATE_NPB 64                                  // nodes per gate block (200000/64 = 3125 exact)

typedef unsigned short bfu;

__device__ __forceinline__ float bf2f(bfu u) { return __uint_as_float(((unsigned)u) << 16); }
__device__ __forceinline__ bfu f2bf(float f) {
    unsigned b = __float_as_uint(f);
    return (bfu)((b + 0x7FFF + ((b >> 16) & 1)) >> 16);   // RTNE, finite inputs
}

// out = emb * sigmoid(emb @ W + b). acc-init out1 in fp32, u_cur out2 in bf16.
__global__ void gate_kernel(const float* __restrict__ emb,
                            const float* __restrict__ W,
                            const float* __restrict__ b,
                            float* __restrict__ out1,
                            bfu* __restrict__ out2) {
    __shared__ float4 Wl4[64][16];
    __shared__ float4 bl4[16];
    __shared__ float rowbuf[4][4][72];   // [wave][sub][72] pad: banks differ per sub
    int t = threadIdx.x;
    const float4* Wg4 = (const float4*)W;
    for (int idx = t; idx < 1024; idx += 256) Wl4[idx >> 4][idx & 15] = Wg4[idx];
    if (t < 16) bl4[t] = ((const float4*)b)[t];
    __syncthreads();
    int w = t >> 6, lane = t & 63, sub = lane >> 4, l16 = lane & 15;
    int base = blockIdx.x * GATE_NPB + w * 4;
    const float4* emb4 = (const float4*)emb;
#pragma unroll 1
    for (int it = 0; it < GATE_NPB / 16; ++it, base += 16) {
        int i = base + sub;
        float4 xr = emb4[(size_t)i * 16 + l16];
        *(float4*)&rowbuf[w][sub][l16 * 4] = xr;
        __syncthreads();
        float4 s = bl4[l16];
#pragma unroll 16
        for (int k = 0; k < 64; ++k) {
            float xk = rowbuf[w][sub][k];
            float4 wv = Wl4[k][l16];
            s.x += xk * wv.x; s.y += xk * wv.y; s.z += xk * wv.z; s.w += xk * wv.w;
        }
        float4 g;
        g.x = 1.0f / (1.0f + __expf(-s.x));
        g.y = 1.0f / (1.0f + __expf(-s.y));
        g.z = 1.0f / (1.0f + __expf(-s.z));
        g.w = 1.0f / (1.0f + __expf(-s.w));
        float4 val;
        val.x = xr.x * g.x; val.y = xr.y * g.y; val.z = xr.z * g.z; val.w = xr.w * g.w;
        size_t o4 = (size_t)i * 16 + l16;
        ((float4*)out1)[o4] = val;
        ushort4 bv;
        bv.x = f2bf(val.x); bv.y = f2bf(val.y); bv.z = f2bf(val.z); bv.w = f2bf(val.w);
        ((ushort4*)out2)[o4] = bv;
        __syncthreads();
    }
}

// phase 1: per-block LDS bucket histogram -> bc[bucket*NB + blk]
__global__ void binA_kernel(const int* __restrict__ item_rows,
                            const int* __restrict__ user_rows,
                            int* __restrict__ bc) {
    __shared__ int h[NBUCK];
    int t = threadIdx.x, blk = blockIdx.x;
    for (int k = t; k < NBUCK; k += 256) h[k] = 0;
    __syncthreads();
    int lo = blk * CHUNK, hi = min(lo + CHUNK, TOT_E);
    for (int i = lo + t; i < hi; i += 256) {
        int g = (i < N_EDGES) ? item_rows[i] : (N_NODE + user_rows[i - N_EDGES]);
        atomicAdd(&h[g >> BSHIFT], 1);
    }
    __syncthreads();
    for (int k = t; k < NBUCK; k += 256) bc[k * NB + blk] = h[k];
}

// ---- generic device-wide exclusive scan over SCAN_N ints ----
__global__ void scan1_kernel(const int* __restrict__ cnt, int* __restrict__ bsum, int n) {
    int t = threadIdx.x;
    int base = blockIdx.x * SCAN_CHUNK + t * 4;
    int s = 0;
#pragma unroll
    for (int k = 0; k < 4; ++k) {
        int i = base + k;
        if (i < n) s += cnt[i];
    }
#pragma unroll
    for (int off = 32; off; off >>= 1) s += __shfl_xor(s, off);
    __shared__ int ws[4];
    int lane = t & 63, w = t >> 6;
    if (lane == 0) ws[w] = s;
    __syncthreads();
    if (t == 0) bsum[blockIdx.x] = ws[0] + ws[1] + ws[2] + ws[3];
}

__global__ void scan2_kernel(const int* __restrict__ bsum, int* __restrict__ boff, int nblocks) {
    __shared__ int sh[256];
    int t = threadIdx.x;
    int v = (t < nblocks) ? bsum[t] : 0;
    sh[t] = v;
    __syncthreads();
    for (int off = 1; off < 256; off <<= 1) {
        int u = (t >= off) ? sh[t - off] : 0;
        __syncthreads();
        sh[t] += u;
        __syncthreads();
    }
    if (t < nblocks) boff[t] = sh[t] - v;   // exclusive
}

__global__ void scan3_kernel(const int* __restrict__ cnt, const int* __restrict__ boff,
                             int* __restrict__ out, int n) {
    int t = threadIdx.x;
    int lane = t & 63, w = t >> 6;
    int base = blockIdx.x * SCAN_CHUNK + t * 4;
    int c[4];
#pragma unroll
    for (int k = 0; k < 4; ++k) {
        int i = base + k;
        c[k] = (i < n) ? cnt[i] : 0;
    }
    int e1 = c[0], e2 = c[0] + c[1], e3 = c[0] + c[1] + c[2];
    int tsum = e3 + c[3];
    int incl = tsum;
#pragma unroll
    for (int off = 1; off < 64; off <<= 1) {
        int u = __shfl_up(incl, off);
        if (lane >= off) incl += u;
    }
    int excl = incl - tsum;
    __shared__ int wsum[4];
    if (lane == 63) wsum[w] = incl;
    __syncthreads();
    int woff = 0;
    for (int k = 0; k < 4; ++k) if (k < w) woff += wsum[k];
    int g = boff[blockIdx.x] + woff + excl;
    int vv[4] = {g, g + e1, g + e2, g + e3};
#pragma unroll
    for (int k = 0; k < 4; ++k) {
        int i = base + k;
        if (i < n) out[i] = vv[k];
    }
}

// phase 2: stage edges into (bucket, block)-contiguous ranges; LDS cursors, no global atomics
__global__ void binB_kernel(const int* __restrict__ item_rows, const int* __restrict__ item_cols,
                            const float* __restrict__ item_vals,
                            const int* __restrict__ user_rows, const int* __restrict__ user_cols,
                            const float* __restrict__ user_vals,
                            const int* __restrict__ soff, int2* __restrict__ staged) {
    __shared__ int cur[NBUCK];
    int t = threadIdx.x, blk = blockIdx.x;
    for (int k = t; k < NBUCK; k += 256) cur[k] = soff[k * NB + blk];
    __syncthreads();
    int lo = blk * CHUNK, hi = min(lo + CHUNK, TOT_E);
    for (int i = lo + t; i < hi; i += 256) {
        int g, c; float v;
        if (i < N_EDGES) { g = item_rows[i]; c = item_cols[i]; v = item_vals[i]; }
        else { int j = i - N_EDGES; g = N_NODE + user_rows[j]; c = user_cols[j]; v = user_vals[j]; }
        int pos = atomicAdd(&cur[g >> BSHIFT], 1);
        staged[pos] = make_int2(((g & (BROWS - 1)) << 18) | c, __float_as_int(v));
    }
}

// phase 3: one WG per bucket: LDS row-hist + scan -> row_ptr; local scatter -> ecv
__global__ void finalize_kernel(const int2* __restrict__ staged, const int* __restrict__ soff,
                                int* __restrict__ row_ptr, int2* __restrict__ ecv) {
    __shared__ int hist[BROWS];
    __shared__ int cur[BROWS];
    __shared__ int wsum[4];
    int b = blockIdx.x, t = threadIdx.x;
    int base = soff[b * NB];
    int end = (b + 1 < NBUCK) ? soff[(b + 1) * NB] : TOT_E;
    for (int k = t; k < BROWS; k += 256) hist[k] = 0;
    __syncthreads();
    for (int k = base + t; k < end; k += 256)
        atomicAdd(&hist[staged[k].x >> 18], 1);
    __syncthreads();
    int i0 = t * 4;
    int c0 = hist[i0], c1 = hist[i0 + 1], c2 = hist[i0 + 2], c3 = hist[i0 + 3];
    int tsum = c0 + c1 + c2 + c3;
    int lane = t & 63, w = t >> 6;
    int incl = tsum;
#pragma unroll
    for (int off = 1; off < 64; off <<= 1) {
        int u = __shfl_up(incl, off);
        if (lane >= off) incl += u;
    }
    if (lane == 63) wsum[w] = incl;
    __syncthreads();
    int woff = 0;
    for (int k = 0; k < w; ++k) woff += wsum[k];
    int start = base + woff + incl - tsum;
    int g0 = (b << BSHIFT) + i0;
    int s0 = start, s1 = start + c0, s2 = s1 + c1, s3 = s2 + c2;
    if (g0 + 0 < NROWS_TOTAL) row_ptr[g0 + 0] = s0;
    if (g0 + 1 < NROWS_TOTAL) row_ptr[g0 + 1] = s1;
    if (g0 + 2 < NROWS_TOTAL) row_ptr[g0 + 2] = s2;
    if (g0 + 3 < NROWS_TOTAL) row_ptr[g0 + 3] = s3;
    cur[i0] = s0; cur[i0 + 1] = s1; cur[i0 + 2] = s2; cur[i0 + 3] = s3;
    if (b == 0 && t == 0) row_ptr[NROWS_TOTAL] = TOT_E;
    __syncthreads();
    for (int k = base + t; k < end; k += 256) {
        int2 p = staged[k];
        int gl = p.x >> 18;
        int pos = atomicAdd(&cur[gl], 1);
        ecv[pos] = make_int2(p.x & 0x3FFFF, p.y);
    }
}

// 16 lanes per row, 4 rows per wave; bf16 gather operand (128B rows), fp32 accumulate.
template <bool WRITE_Y>
__global__ void spmm_norm_acc(const int* __restrict__ row_ptr, const int2* __restrict__ ecv,
                              const bfu* __restrict__ x,
                              bfu* __restrict__ y, float* __restrict__ acc, int n) {
    int t = threadIdx.x;
    int lane = t & 63;
    int sub = lane >> 4;
    int l16 = lane & 15;
    int i = blockIdx.x * 16 + (t >> 6) * 4 + sub;
    if (i >= n) return;
    int s = row_ptr[i], e = row_ptr[i + 1];
    const ushort4* x4 = (const ushort4*)x;
    float4 a = make_float4(0.f, 0.f, 0.f, 0.f);
    int gbase = sub * 16;
    for (int base = s; base < e; base += 16) {
        int idx = base + l16;
        int cl = 0; float vl = 0.0f;
        if (idx < e) { int2 p = ecv[idx]; cl = p.x; vl = __int_as_float(p.y); }
        int cnt = min(16, e - base);
        int cnt4 = (cnt + 3) & ~3;
        for (int k = 0; k < cnt4; k += 4) {
#pragma unroll
            for (int u = 0; u < 4; ++u) {
                int c = __shfl(cl, gbase + k + u);
                float v = __shfl(vl, gbase + k + u);
                ushort4 xv = x4[(size_t)c * 16 + l16];
                a.x += v * bf2f(xv.x); a.y += v * bf2f(xv.y);
                a.z += v * bf2f(xv.z); a.w += v * bf2f(xv.w);
            }
        }
    }
    size_t o4 = (size_t)i * 16 + l16;
    if (WRITE_Y) {
        ushort4 bv;
        bv.x = f2bf(a.x); bv.y = f2bf(a.y); bv.z = f2bf(a.z); bv.w = f2bf(a.w);
        ((ushort4*)y)[o4] = bv;
    }
    float sq = a.x * a.x + a.y * a.y + a.z * a.z + a.w * a.w;
#pragma unroll
    for (int off = 8; off; off >>= 1) sq += __shfl_xor(sq, off);
    float rinv = 1.0f / fmaxf(sqrtf(sq), 1e-12f);
    float4* acc4 = (float4*)acc;
    float4 aa = acc4[o4];
    aa.x += a.x * rinv; aa.y += a.y * rinv; aa.z += a.z * rinv; aa.w += a.w * rinv;
    acc4[o4] = aa;
}

// channel-3 last layer fused with channel attention + mix
__global__ void spmm_norm_mix(const int* __restrict__ row_ptr, const int2* __restrict__ ecv,
                              const bfu* __restrict__ x, const float* __restrict__ acc3,
                              float* __restrict__ mixed, const float* __restrict__ vvec,
                              float* __restrict__ score, int n) {
    int t = threadIdx.x;
    int lane = t & 63;
    int sub = lane >> 4;
    int l16 = lane & 15;
    int i = blockIdx.x * 16 + (t >> 6) * 4 + sub;
    if (i >= n) return;
    int s = row_ptr[i], e = row_ptr[i + 1];
    const ushort4* x4 = (const ushort4*)x;
    float4 a = make_float4(0.f, 0.f, 0.f, 0.f);
    int gbase = sub * 16;
    for (int base = s; base < e; base += 16) {
        int idx = base + l16;
        int cl = 0; float vl = 0.0f;
        if (idx < e) { int2 p = ecv[idx]; cl = p.x; vl = __int_as_float(p.y); }
        int cnt = min(16, e - base);
        int cnt4 = (cnt + 3) & ~3;
        for (int k = 0; k < cnt4; k += 4) {
#pragma unroll
            for (int u = 0; u < 4; ++u) {
                int c = __shfl(cl, gbase + k + u);
                float v = __shfl(vl, gbase + k + u);
                ushort4 xv = x4[(size_t)c * 16 + l16];
                a.x += v * bf2f(xv.x); a.y += v * bf2f(xv.y);
                a.z += v * bf2f(xv.z); a.w += v * bf2f(xv.w);
            }
        }
    }
    float sq = a.x * a.x + a.y * a.y + a.z * a.z + a.w * a.w;
#pragma unroll
    for (int off = 8; off; off >>= 1) sq += __shfl_xor(sq, off);
    float rinv = 1.0f / fmaxf(sqrtf(sq), 1e-12f);
    size_t o4 = (size_t)i * 16 + l16;
    float4 a3 = ((const float4*)acc3)[o4];
    a3.x += a.x * rinv; a3.y += a.y * rinv; a3.z += a.z * rinv; a3.w += a.w * rinv;
    float4 a2 = ((float4*)mixed)[o4];
    float4 vv = ((const float4*)vvec)[l16];
    float w2 = a2.x * vv.x + a2.y * vv.y + a2.z * vv.z + a2.w * vv.w;
    float w3 = a3.x * vv.x + a3.y * vv.y + a3.z * vv.z + a3.w * vv.w;
#pragma unroll
    for (int off = 8; off; off >>= 1) {
        w2 += __shfl_xor(w2, off);
        w3 += __shfl_xor(w3, off);
    }
    float m = fmaxf(w2, w3);
    float x2 = __expf(w2 - m), x3 = __expf(w3 - m);
    float inv = 1.0f / (x2 + x3);
    float s2 = x2 * inv, s3 = x3 * inv;
    float4 o;
    o.x = s2 * a2.x + s3 * a3.x; o.y = s2 * a2.y + s3 * a3.y;
    o.z = s2 * a2.z + s3 * a3.z; o.w = s2 * a2.w + s3 * a3.w;
    ((float4*)mixed)[o4] = o;
    if (l16 == 0) { score[(size_t)i * 2] = s2; score[(size_t)i * 2 + 1] = s3; }
}

// v[k] = sum_j att_m[k][j] * att[j]
__global__ void vvec_kernel(const float* __restrict__ att_m, const float* __restrict__ att,
                            float* __restrict__ v) {
    int k = threadIdx.x;
    float s = 0.0f;
    for (int j = 0; j < 64; ++j) s += att_m[k * 64 + j] * att[j];
    v[k] = s;
}

extern "C" void kernel_launch(void* const* d_in, const int* in_sizes, int n_in,
                              void* d_out, int out_size, void* d_ws, size_t ws_size,
                              hipStream_t stream) {
    const float* user_emb = (const float*)d_in[0];
    const float* W0 = (const float*)d_in[1];
    const float* b0 = (const float*)d_in[2];
    const float* W1 = (const float*)d_in[3];
    const float* b1 = (const float*)d_in[4];
    const float* att = (const float*)d_in[5];
    const float* att_m = (const float*)d_in[6];
    const int* item_rows = (const int*)d_in[7];
    const int* item_cols = (const int*)d_in[8];
    const float* item_vals = (const float*)d_in[9];
    const int* user_rows = (const int*)d_in[10];
    const int* user_cols = (const int*)d_in[11];
    const float* user_vals = (const float*)d_in[12];

    float* out = (float*)d_out;
    float* mixed = out;                          // N*64, doubles as acc2
    float* score = out + (size_t)N_NODE * 64;

    char* w = (char*)d_ws;
    float* acc3 = (float*)w;   w += (size_t)N_NODE * 64 * 4;
    bfu* u_cur = (bfu*)w;      w += (size_t)N_NODE * 64 * 2;   // bf16
    bfu* u_nxt = (bfu*)w;      w += (size_t)N_NODE * 64 * 2;   // bf16
    int* row_ptr = (int*)w;    w += ((size_t)NROWS_TOTAL + 64) * 4;
    int2* ecv = (int2*)w;      w += (size_t)TOT_E * 8;
    float* vvec = (float*)w;   w += 256;
    int* bc = (int*)w;         w += (size_t)SCAN_N * 4;        // per-(bucket,block) counts
    int* soff = (int*)w;       w += (size_t)SCAN_N * 4;        // scanned offsets
    int* bsum = (int*)w;       w += 1024;
    int* boff = (int*)w;       w += 1024;
    int2* staged = (int2*)u_cur;   // overlays u_cur+u_nxt (51.2MB >= 32MB), dead during build

    const int NB16 = (N_NODE + 15) / 16;
    const int GATE_B = N_NODE / GATE_NPB;       // 3125 exact
    const int* rp_item = row_ptr;
    const int* rp_user = row_ptr + N_NODE;

    // counting-sort CSR build (both graphs in one indexing space), no global atomics
    binA_kernel<<<NB, 256, 0, stream>>>(item_rows, user_rows, bc);
    scan1_kernel<<<SCAN_BLOCKS, 256, 0, stream>>>(bc, bsum, SCAN_N);
    scan2_kernel<<<1, 256, 0, stream>>>(bsum, boff, SCAN_BLOCKS);
    scan3_kernel<<<SCAN_BLOCKS, 256, 0, stream>>>(bc, boff, soff, SCAN_N);
    binB_kernel<<<NB, 256, 0, stream>>>(item_rows, item_cols, item_vals,
                                        user_rows, user_cols, user_vals, soff, staged);
    finalize_kernel<<<NBUCK, 256, 0, stream>>>(staged, soff, row_ptr, ecv);
    vvec_kernel<<<1, 64, 0, stream>>>(att_m, att, vvec);

    // channel 2: item graph, acc lives in d_out (mixed region)
    gate_kernel<<<GATE_B, 256, 0, stream>>>(user_emb, W0, b0, mixed, u_cur);
    spmm_norm_acc<true><<<NB16, 256, 0, stream>>>(rp_item, ecv, u_cur, u_nxt, mixed, N_NODE);
    spmm_norm_acc<true><<<NB16, 256, 0, stream>>>(rp_item, ecv, u_nxt, u_cur, mixed, N_NODE);
    spmm_norm_acc<false><<<NB16, 256, 0, stream>>>(rp_item, ecv, u_cur, nullptr, mixed, N_NODE);

    // channel 3: user graph
    gate_kernel<<<GATE_B, 256, 0, stream>>>(user_emb, W1, b1, acc3, u_cur);
    spmm_norm_acc<true><<<NB16, 256, 0, stream>>>(rp_user, ecv, u_cur, u_nxt, acc3, N_NODE);
    spmm_norm_acc<true><<<NB16, 256, 0, stream>>>(rp_user, ecv, u_nxt, u_cur, acc3, N_NODE);
    spmm_norm_mix<<<NB16, 256, 0, stream>>>(rp_user, ecv, u_cur, acc3, mixed, vvec, score, N_NODE);
}

// Round 9
// 531.836 us; speedup vs baseline: 3.2287x; 1.0587x over previous
//
#include <hip/hip_runtime.h>

#define N_NODE 200000
#define EMB 64
#define N_EDGES 2000000
#define NROWS_TOTAL (2 * N_NODE)        // both graphs' rows concatenated
#define TOT_E (2 * N_EDGES)

// counting-sort geometry
#define BSHIFT 10
#define BROWS 1024                                   // rows per bucket
#define NBUCK ((NROWS_TOTAL + BROWS - 1) / BROWS)    // 391
#define NB 1024                                      // binning blocks (4 blocks/CU)
#define CHUNK ((TOT_E + NB - 1) / NB)                // 3907 edges per block
#define SCAN_N (NBUCK * NB)                          // 400384
#define SCAN_CHUNK 1024
#define SCAN_BLOCKS ((SCAN_N + SCAN_CHUNK - 1) / SCAN_CHUNK)  // 391

#define GATE_NPB 64                                  // nodes per gate block (200000/64 = 3125 exact)

typedef unsigned short bfu;

__device__ __forceinline__ float bf2f(bfu u) { return __uint_as_float(((unsigned)u) << 16); }
__device__ __forceinline__ bfu f2bf(float f) {
    unsigned b = __float_as_uint(f);
    return (bfu)((b + 0x7FFF + ((b >> 16) & 1)) >> 16);   // RTNE, finite inputs
}

// out = emb * sigmoid(emb @ W + b), bf16 output only (acc handled by deferred sum)
__global__ void gate_kernel(const float* __restrict__ emb,
                            const float* __restrict__ W,
                            const float* __restrict__ b,
                            bfu* __restrict__ out) {
    __shared__ float4 Wl4[64][16];
    __shared__ float4 bl4[16];
    __shared__ float rowbuf[4][4][72];   // [wave][sub][72] pad: banks differ per sub
    int t = threadIdx.x;
    const float4* Wg4 = (const float4*)W;
    for (int idx = t; idx < 1024; idx += 256) Wl4[idx >> 4][idx & 15] = Wg4[idx];
    if (t < 16) bl4[t] = ((const float4*)b)[t];
    __syncthreads();
    int w = t >> 6, lane = t & 63, sub = lane >> 4, l16 = lane & 15;
    int base = blockIdx.x * GATE_NPB + w * 4;
    const float4* emb4 = (const float4*)emb;
#pragma unroll 1
    for (int it = 0; it < GATE_NPB / 16; ++it, base += 16) {
        int i = base + sub;
        float4 xr = emb4[(size_t)i * 16 + l16];
        *(float4*)&rowbuf[w][sub][l16 * 4] = xr;
        __syncthreads();
        float4 s = bl4[l16];
#pragma unroll 16
        for (int k = 0; k < 64; ++k) {
            float xk = rowbuf[w][sub][k];
            float4 wv = Wl4[k][l16];
            s.x += xk * wv.x; s.y += xk * wv.y; s.z += xk * wv.z; s.w += xk * wv.w;
        }
        float4 g;
        g.x = 1.0f / (1.0f + __expf(-s.x));
        g.y = 1.0f / (1.0f + __expf(-s.y));
        g.z = 1.0f / (1.0f + __expf(-s.z));
        g.w = 1.0f / (1.0f + __expf(-s.w));
        ushort4 bv;
        bv.x = f2bf(xr.x * g.x); bv.y = f2bf(xr.y * g.y);
        bv.z = f2bf(xr.z * g.z); bv.w = f2bf(xr.w * g.w);
        ((ushort4*)out)[(size_t)i * 16 + l16] = bv;
        __syncthreads();
    }
}

// phase 1: per-block LDS bucket histogram -> bc[bucket*NB + blk]
__global__ void binA_kernel(const int* __restrict__ item_rows,
                            const int* __restrict__ user_rows,
                            int* __restrict__ bc) {
    __shared__ int h[NBUCK];
    int t = threadIdx.x, blk = blockIdx.x;
    for (int k = t; k < NBUCK; k += 256) h[k] = 0;
    __syncthreads();
    int lo = blk * CHUNK, hi = min(lo + CHUNK, TOT_E);
    for (int i = lo + t; i < hi; i += 256) {
        int g = (i < N_EDGES) ? item_rows[i] : (N_NODE + user_rows[i - N_EDGES]);
        atomicAdd(&h[g >> BSHIFT], 1);
    }
    __syncthreads();
    for (int k = t; k < NBUCK; k += 256) bc[k * NB + blk] = h[k];
}

// ---- generic device-wide exclusive scan over SCAN_N ints ----
__global__ void scan1_kernel(const int* __restrict__ cnt, int* __restrict__ bsum, int n) {
    int t = threadIdx.x;
    int base = blockIdx.x * SCAN_CHUNK + t * 4;
    int s = 0;
#pragma unroll
    for (int k = 0; k < 4; ++k) {
        int i = base + k;
        if (i < n) s += cnt[i];
    }
#pragma unroll
    for (int off = 32; off; off >>= 1) s += __shfl_xor(s, off);
    __shared__ int ws[4];
    int lane = t & 63, w = t >> 6;
    if (lane == 0) ws[w] = s;
    __syncthreads();
    if (t == 0) bsum[blockIdx.x] = ws[0] + ws[1] + ws[2] + ws[3];
}

__global__ void scan2_kernel(const int* __restrict__ bsum, int* __restrict__ boff, int nblocks) {
    __shared__ int sh[512];
    int t = threadIdx.x;   // 512 threads
    int v = (t < nblocks) ? bsum[t] : 0;
    sh[t] = v;
    __syncthreads();
    for (int off = 1; off < 512; off <<= 1) {
        int u = (t >= off) ? sh[t - off] : 0;
        __syncthreads();
        sh[t] += u;
        __syncthreads();
    }
    if (t < nblocks) boff[t] = sh[t] - v;   // exclusive
}

__global__ void scan3_kernel(const int* __restrict__ cnt, const int* __restrict__ boff,
                             int* __restrict__ out, int n) {
    int t = threadIdx.x;
    int lane = t & 63, w = t >> 6;
    int base = blockIdx.x * SCAN_CHUNK + t * 4;
    int c[4];
#pragma unroll
    for (int k = 0; k < 4; ++k) {
        int i = base + k;
        c[k] = (i < n) ? cnt[i] : 0;
    }
    int e1 = c[0], e2 = c[0] + c[1], e3 = c[0] + c[1] + c[2];
    int tsum = e3 + c[3];
    int incl = tsum;
#pragma unroll
    for (int off = 1; off < 64; off <<= 1) {
        int u = __shfl_up(incl, off);
        if (lane >= off) incl += u;
    }
    int excl = incl - tsum;
    __shared__ int wsum[4];
    if (lane == 63) wsum[w] = incl;
    __syncthreads();
    int woff = 0;
    for (int k = 0; k < 4; ++k) if (k < w) woff += wsum[k];
    int g = boff[blockIdx.x] + woff + excl;
    int vv[4] = {g, g + e1, g + e2, g + e3};
#pragma unroll
    for (int k = 0; k < 4; ++k) {
        int i = base + k;
        if (i < n) out[i] = vv[k];
    }
}

// phase 2: stage edges into (bucket, block)-contiguous ranges; LDS cursors, no global atomics
__global__ void binB_kernel(const int* __restrict__ item_rows, const int* __restrict__ item_cols,
                            const float* __restrict__ item_vals,
                            const int* __restrict__ user_rows, const int* __restrict__ user_cols,
                            const float* __restrict__ user_vals,
                            const int* __restrict__ soff, int2* __restrict__ staged) {
    __shared__ int cur[NBUCK];
    int t = threadIdx.x, blk = blockIdx.x;
    for (int k = t; k < NBUCK; k += 256) cur[k] = soff[k * NB + blk];
    __syncthreads();
    int lo = blk * CHUNK, hi = min(lo + CHUNK, TOT_E);
    for (int i = lo + t; i < hi; i += 256) {
        int g, c; float v;
        if (i < N_EDGES) { g = item_rows[i]; c = item_cols[i]; v = item_vals[i]; }
        else { int j = i - N_EDGES; g = N_NODE + user_rows[j]; c = user_cols[j]; v = user_vals[j]; }
        int pos = atomicAdd(&cur[g >> BSHIFT], 1);
        staged[pos] = make_int2(((g & (BROWS - 1)) << 18) | c, __float_as_int(v));
    }
}

// phase 3: one WG per bucket: LDS row-hist + scan -> row_ptr; local scatter -> ecv
__global__ void finalize_kernel(const int2* __restrict__ staged, const int* __restrict__ soff,
                                int* __restrict__ row_ptr, int2* __restrict__ ecv) {
    __shared__ int hist[BROWS];
    __shared__ int cur[BROWS];
    __shared__ int wsum[4];
    int b = blockIdx.x, t = threadIdx.x;
    int base = soff[b * NB];
    int end = (b + 1 < NBUCK) ? soff[(b + 1) * NB] : TOT_E;
    for (int k = t; k < BROWS; k += 256) hist[k] = 0;
    __syncthreads();
    for (int k = base + t; k < end; k += 256)
        atomicAdd(&hist[staged[k].x >> 18], 1);
    __syncthreads();
    int i0 = t * 4;
    int c0 = hist[i0], c1 = hist[i0 + 1], c2 = hist[i0 + 2], c3 = hist[i0 + 3];
    int tsum = c0 + c1 + c2 + c3;
    int lane = t & 63, w = t >> 6;
    int incl = tsum;
#pragma unroll
    for (int off = 1; off < 64; off <<= 1) {
        int u = __shfl_up(incl, off);
        if (lane >= off) incl += u;
    }
    if (lane == 63) wsum[w] = incl;
    __syncthreads();
    int woff = 0;
    for (int k = 0; k < w; ++k) woff += wsum[k];
    int start = base + woff + incl - tsum;
    int g0 = (b << BSHIFT) + i0;
    int s0 = start, s1 = start + c0, s2 = s1 + c1, s3 = s2 + c2;
    if (g0 + 0 < NROWS_TOTAL) row_ptr[g0 + 0] = s0;
    if (g0 + 1 < NROWS_TOTAL) row_ptr[g0 + 1] = s1;
    if (g0 + 2 < NROWS_TOTAL) row_ptr[g0 + 2] = s2;
    if (g0 + 3 < NROWS_TOTAL) row_ptr[g0 + 3] = s3;
    cur[i0] = s0; cur[i0 + 1] = s1; cur[i0 + 2] = s2; cur[i0 + 3] = s3;
    if (b == 0 && t == 0) row_ptr[NROWS_TOTAL] = TOT_E;
    __syncthreads();
    for (int k = base + t; k < end; k += 256) {
        int2 p = staged[k];
        int gl = p.x >> 18;
        int pos = atomicAdd(&cur[gl], 1);
        ecv[pos] = make_int2(p.x & 0x3FFFF, p.y);
    }
}

// y = A x (bf16 gather, fp32 accumulate), write y bf16 + per-row rinv scalar.
__global__ void spmm_y(const int* __restrict__ row_ptr, const int2* __restrict__ ecv,
                       const bfu* __restrict__ x,
                       bfu* __restrict__ y, float* __restrict__ rinv, int n) {
    int t = threadIdx.x;
    int lane = t & 63;
    int sub = lane >> 4;
    int l16 = lane & 15;
    int i = blockIdx.x * 16 + (t >> 6) * 4 + sub;
    if (i >= n) return;
    int s = row_ptr[i], e = row_ptr[i + 1];
    const ushort4* x4 = (const ushort4*)x;
    float4 a = make_float4(0.f, 0.f, 0.f, 0.f);
    int gbase = sub * 16;
    for (int base = s; base < e; base += 16) {
        int idx = base + l16;
        int cl = 0; float vl = 0.0f;
        if (idx < e) { int2 p = ecv[idx]; cl = p.x; vl = __int_as_float(p.y); }
        int cnt = min(16, e - base);
        int cnt4 = (cnt + 3) & ~3;
        for (int k = 0; k < cnt4; k += 4) {
#pragma unroll
            for (int u = 0; u < 4; ++u) {
                int c = __shfl(cl, gbase + k + u);
                float v = __shfl(vl, gbase + k + u);
                ushort4 xv = x4[(size_t)c * 16 + l16];
                a.x += v * bf2f(xv.x); a.y += v * bf2f(xv.y);
                a.z += v * bf2f(xv.z); a.w += v * bf2f(xv.w);
            }
        }
    }
    size_t o4 = (size_t)i * 16 + l16;
    ushort4 bv;
    bv.x = f2bf(a.x); bv.y = f2bf(a.y); bv.z = f2bf(a.z); bv.w = f2bf(a.w);
    ((ushort4*)y)[o4] = bv;
    float sq = a.x * a.x + a.y * a.y + a.z * a.z + a.w * a.w;
#pragma unroll
    for (int off = 8; off; off >>= 1) sq += __shfl_xor(sq, off);
    if (l16 == 0) rinv[i] = 1.0f / fmaxf(sqrtf(sq), 1e-12f);
}

// channel-2 sum: out = u0 + r1*y1 + r2*y2 + r3*y3 (fp32)
__global__ void sum_kernel(const bfu* __restrict__ u0, const bfu* __restrict__ y1,
                           const bfu* __restrict__ y2, const bfu* __restrict__ y3,
                           const float* __restrict__ r1, const float* __restrict__ r2,
                           const float* __restrict__ r3, float* __restrict__ outv, int n) {
    int t = threadIdx.x;
    int lane = t & 63;
    int sub = lane >> 4;
    int l16 = lane & 15;
    int i = blockIdx.x * 16 + (t >> 6) * 4 + sub;
    if (i >= n) return;
    size_t o4 = (size_t)i * 16 + l16;
    float a1 = r1[i], a2 = r2[i], a3 = r3[i];
    ushort4 b0 = ((const ushort4*)u0)[o4];
    ushort4 b1 = ((const ushort4*)y1)[o4];
    ushort4 b2 = ((const ushort4*)y2)[o4];
    ushort4 b3 = ((const ushort4*)y3)[o4];
    float4 o;
    o.x = bf2f(b0.x) + a1 * bf2f(b1.x) + a2 * bf2f(b2.x) + a3 * bf2f(b3.x);
    o.y = bf2f(b0.y) + a1 * bf2f(b1.y) + a2 * bf2f(b2.y) + a3 * bf2f(b3.y);
    o.z = bf2f(b0.z) + a1 * bf2f(b1.z) + a2 * bf2f(b2.z) + a3 * bf2f(b3.z);
    o.w = bf2f(b0.w) + a1 * bf2f(b1.w) + a2 * bf2f(b2.w) + a3 * bf2f(b3.w);
    ((float4*)outv)[o4] = o;
}

// final: e3 = u0 + Σ r_L y_L; e2 = mixed (fp32); channel attention softmax; write mixed + score
__global__ void mix_kernel(const bfu* __restrict__ u0, const bfu* __restrict__ y1,
                           const bfu* __restrict__ y2, const bfu* __restrict__ y3,
                           const float* __restrict__ r1, const float* __restrict__ r2,
                           const float* __restrict__ r3,
                           float* __restrict__ mixed, const float* __restrict__ vvec,
                           float* __restrict__ score, int n) {
    int t = threadIdx.x;
    int lane = t & 63;
    int sub = lane >> 4;
    int l16 = lane & 15;
    int i = blockIdx.x * 16 + (t >> 6) * 4 + sub;
    if (i >= n) return;
    size_t o4 = (size_t)i * 16 + l16;
    float a1 = r1[i], a2s = r2[i], a3s = r3[i];
    ushort4 b0 = ((const ushort4*)u0)[o4];
    ushort4 b1 = ((const ushort4*)y1)[o4];
    ushort4 b2 = ((const ushort4*)y2)[o4];
    ushort4 b3 = ((const ushort4*)y3)[o4];
    float4 a3;
    a3.x = bf2f(b0.x) + a1 * bf2f(b1.x) + a2s * bf2f(b2.x) + a3s * bf2f(b3.x);
    a3.y = bf2f(b0.y) + a1 * bf2f(b1.y) + a2s * bf2f(b2.y) + a3s * bf2f(b3.y);
    a3.z = bf2f(b0.z) + a1 * bf2f(b1.z) + a2s * bf2f(b2.z) + a3s * bf2f(b3.z);
    a3.w = bf2f(b0.w) + a1 * bf2f(b1.w) + a2s * bf2f(b2.w) + a3s * bf2f(b3.w);
    float4 a2 = ((float4*)mixed)[o4];
    float4 vv = ((const float4*)vvec)[l16];
    float w2 = a2.x * vv.x + a2.y * vv.y + a2.z * vv.z + a2.w * vv.w;
    float w3 = a3.x * vv.x + a3.y * vv.y + a3.z * vv.z + a3.w * vv.w;
#pragma unroll
    for (int off = 8; off; off >>= 1) {
        w2 += __shfl_xor(w2, off);
        w3 += __shfl_xor(w3, off);
    }
    float m = fmaxf(w2, w3);
    float x2 = __expf(w2 - m), x3 = __expf(w3 - m);
    float inv = 1.0f / (x2 + x3);
    float s2 = x2 * inv, s3 = x3 * inv;
    float4 o;
    o.x = s2 * a2.x + s3 * a3.x; o.y = s2 * a2.y + s3 * a3.y;
    o.z = s2 * a2.z + s3 * a3.z; o.w = s2 * a2.w + s3 * a3.w;
    ((float4*)mixed)[o4] = o;
    if (l16 == 0) { score[(size_t)i * 2] = s2; score[(size_t)i * 2 + 1] = s3; }
}

// v[k] = sum_j att_m[k][j] * att[j]
__global__ void vvec_kernel(const float* __restrict__ att_m, const float* __restrict__ att,
                            float* __restrict__ v) {
    int k = threadIdx.x;
    float s = 0.0f;
    for (int j = 0; j < 64; ++j) s += att_m[k * 64 + j] * att[j];
    v[k] = s;
}

extern "C" void kernel_launch(void* const* d_in, const int* in_sizes, int n_in,
                              void* d_out, int out_size, void* d_ws, size_t ws_size,
                              hipStream_t stream) {
    const float* user_emb = (const float*)d_in[0];
    const float* W0 = (const float*)d_in[1];
    const float* b0 = (const float*)d_in[2];
    const float* W1 = (const float*)d_in[3];
    const float* b1 = (const float*)d_in[4];
    const float* att = (const float*)d_in[5];
    const float* att_m = (const float*)d_in[6];
    const int* item_rows = (const int*)d_in[7];
    const int* item_cols = (const int*)d_in[8];
    const float* item_vals = (const float*)d_in[9];
    const int* user_rows = (const int*)d_in[10];
    const int* user_cols = (const int*)d_in[11];
    const float* user_vals = (const float*)d_in[12];

    float* out = (float*)d_out;
    float* mixed = out;                          // N*64 fp32, holds channel-2 sum then final
    float* score = out + (size_t)N_NODE * 64;

    char* w = (char*)d_ws;
    bfu* u0 = (bfu*)w;         w += (size_t)N_NODE * 64 * 2;
    bfu* y1 = (bfu*)w;         w += (size_t)N_NODE * 64 * 2;
    bfu* y2 = (bfu*)w;         w += (size_t)N_NODE * 64 * 2;
    bfu* y3 = (bfu*)w;         w += (size_t)N_NODE * 64 * 2;
    float* rv1 = (float*)w;    w += (size_t)N_NODE * 4;
    float* rv2 = (float*)w;    w += (size_t)N_NODE * 4;
    float* rv3 = (float*)w;    w += (size_t)N_NODE * 4;
    int* row_ptr = (int*)w;    w += ((size_t)NROWS_TOTAL + 64) * 4;
    int2* ecv = (int2*)w;      w += (size_t)TOT_E * 8;
    float* vvec = (float*)w;   w += 256;
    int* bc = (int*)w;         w += (size_t)SCAN_N * 4;
    int* soff = (int*)w;       w += (size_t)SCAN_N * 4;
    int* bsum = (int*)w;       w += 2048;
    int* boff = (int*)w;       w += 2048;
    int2* staged = (int2*)u0;  // overlays u0+y1 (51.2MB >= 32MB), dead during build

    const int NB16 = (N_NODE + 15) / 16;
    const int GATE_B = N_NODE / GATE_NPB;       // 3125 exact
    const int* rp_item = row_ptr;
    const int* rp_user = row_ptr + N_NODE;

    // counting-sort CSR build (both graphs in one indexing space), no global atomics
    binA_kernel<<<NB, 256, 0, stream>>>(item_rows, user_rows, bc);
    scan1_kernel<<<SCAN_BLOCKS, 256, 0, stream>>>(bc, bsum, SCAN_N);
    scan2_kernel<<<1, 512, 0, stream>>>(bsum, boff, SCAN_BLOCKS);
    scan3_kernel<<<SCAN_BLOCKS, 256, 0, stream>>>(bc, boff, soff, SCAN_N);
    binB_kernel<<<NB, 256, 0, stream>>>(item_rows, item_cols, item_vals,
                                        user_rows, user_cols, user_vals, soff, staged);
    finalize_kernel<<<NBUCK, 256, 0, stream>>>(staged, soff, row_ptr, ecv);
    vvec_kernel<<<1, 64, 0, stream>>>(att_m, att, vvec);

    // channel 2: item graph -> fp32 sum in mixed
    gate_kernel<<<GATE_B, 256, 0, stream>>>(user_emb, W0, b0, u0);
    spmm_y<<<NB16, 256, 0, stream>>>(rp_item, ecv, u0, y1, rv1, N_NODE);
    spmm_y<<<NB16, 256, 0, stream>>>(rp_item, ecv, y1, y2, rv2, N_NODE);
    spmm_y<<<NB16, 256, 0, stream>>>(rp_item, ecv, y2, y3, rv3, N_NODE);
    sum_kernel<<<NB16, 256, 0, stream>>>(u0, y1, y2, y3, rv1, rv2, rv3, mixed, N_NODE);

    // channel 3: user graph, fused sum + attention + mix
    gate_kernel<<<GATE_B, 256, 0, stream>>>(user_emb, W1, b1, u0);
    spmm_y<<<NB16, 256, 0, stream>>>(rp_user, ecv, u0, y1, rv1, N_NODE);
    spmm_y<<<NB16, 256, 0, stream>>>(rp_user, ecv, y1, y2, rv2, N_NODE);
    spmm_y<<<NB16, 256, 0, stream>>>(rp_user, ecv, y2, y3, rv3, N_NODE);
    mix_kernel<<<NB16, 256, 0, stream>>>(u0, y1, y2, y3, rv1, rv2, rv3,
                                         mixed, vvec, score, N_NODE);
}